// Round 6
// baseline (322.993 us; speedup 1.0000x reference)
//
#include <hip/hip_runtime.h>
#include <math.h>

// ---------------------------------------------------------------------------
// Chamfer distance via MFMA (gfx950) — round 6.
//
// d2(p,g) = p^2 + g^2 - 2 p.g computed entirely inside
// v_mfma_f32_32x32x16_bf16 via bf16 hi/lo (Dekker) split over K=16 slots
// (HW-verified absmax 0.0, rounds 1-5).
//
// Evidence so far: r2 (1024 blocks, VGPR 60, spill-free) = 123 us, VALUBusy
// 20%; r5 (same body, 2048 blocks) = 172 us despite higher occupancy -> the
// limiter is the per-wave serial chain (L2-latency B loads under shallow
// unroll), NOT TLP. This round keeps r2's exact config and body except ONE
// change: the block's 16 KB B-slice is staged once into LDS and the inner
// loop reads fragments via ds_read_b128 (lane-linear 16B stride, conflict-
// free, compile-time offsets, fully unrolled) -> deeper pipelining, no L1
// thrash, no per-step address arithmetic.
// ---------------------------------------------------------------------------

constexpr int NPTS  = 16384;
constexpr int BLOCK = 256;                        // 4 waves
constexpr int WAVES = BLOCK / 64;

constexpr int ROWS_PER_BLOCK = 512;
constexpr int COLS_PER_BLOCK = 512;
constexpr int NBX = NPTS / ROWS_PER_BLOCK;        // 32
constexpr int NBY = NPTS / COLS_PER_BLOCK;        // 32
constexpr int NBLOCKS = NBX * NBY;                // 1024
constexpr int ROWS_PER_WAVE = ROWS_PER_BLOCK / WAVES;   // 128
constexpr int ATILES = ROWS_PER_WAVE / 32;        // 4
constexpr int CSTEPS = COLS_PER_BLOCK / 64;       // 8 (two 32-col tiles/step)

typedef __attribute__((ext_vector_type(8)))  __bf16 bf16x8;
typedef __attribute__((ext_vector_type(16))) float  f32x16;

__device__ inline unsigned short f2bf(float f) {          // RNE float->bf16
    unsigned u = __float_as_uint(f);
    u += 0x7FFFu + ((u >> 16) & 1u);
    return (unsigned short)(u >> 16);
}
__device__ inline float bf2f(unsigned short h) {
    return __uint_as_float(((unsigned)h) << 16);
}
__device__ inline unsigned pk(unsigned short lo, unsigned short hi) {
    return (unsigned)lo | ((unsigned)hi << 16);
}

// ---------------------------------------------------------------------------
// Pack to FRAG-READY layout: per point two uint4s (one per k-half), each the
// exact 8-bf16 MFMA fragment for that half (verified layout, rounds 1-5):
//   A half0: [phx,phy,phz, plx,ply,plz, phx,phy]
//   A half1: [phz, p2h, p2l, 1, 1, plx, ply, plz]
//   B half0: [mhx,mhy,mhz, mhx,mhy,mhz, mlx,mly]      (m = -2g)
//   B half1: [mlz, 1, 1, g2h, g2l, mlx, mly, mlz]
// Array layout: half-major — Xf[half*NPTS + i].
// ---------------------------------------------------------------------------
__global__ __launch_bounds__(BLOCK) void pack_init_kernel(
    const float* __restrict__ pred, const float* __restrict__ gt,
    uint4* __restrict__ Af, uint4* __restrict__ Bf,
    unsigned int* __restrict__ minP, unsigned int* __restrict__ minG,
    unsigned int* __restrict__ ticket)
{
    const unsigned short ONE = 0x3F80;
    int i = blockIdx.x * BLOCK + threadIdx.x;
    if (i == 0) *ticket = 0u;
    if (i >= NPTS) return;

    {   // A side (pred)
        float x = pred[3*i], y = pred[3*i+1], z = pred[3*i+2];
        unsigned short hx = f2bf(x), hy = f2bf(y), hz = f2bf(z);
        unsigned short lx = f2bf(x - bf2f(hx));
        unsigned short ly = f2bf(y - bf2f(hy));
        unsigned short lz = f2bf(z - bf2f(hz));
        float p2 = fmaf(x, x, fmaf(y, y, z * z));
        unsigned short sh = f2bf(p2), sl = f2bf(p2 - bf2f(sh));
        uint4 h0, h1;
        h0.x = pk(hx, hy); h0.y = pk(hz, lx); h0.z = pk(ly, lz); h0.w = pk(hx, hy);
        h1.x = pk(hz, sh); h1.y = pk(sl, ONE); h1.z = pk(ONE, lx); h1.w = pk(ly, lz);
        Af[i] = h0;
        Af[NPTS + i] = h1;
    }
    {   // B side (gt, pre-scaled by -2)
        float gx = gt[3*i], gy = gt[3*i+1], gz = gt[3*i+2];
        float mx = -2.0f * gx, my = -2.0f * gy, mz = -2.0f * gz;
        unsigned short hx = f2bf(mx), hy = f2bf(my), hz = f2bf(mz);
        unsigned short lx = f2bf(mx - bf2f(hx));
        unsigned short ly = f2bf(my - bf2f(hy));
        unsigned short lz = f2bf(mz - bf2f(hz));
        float g2 = fmaf(gx, gx, fmaf(gy, gy, gz * gz));
        unsigned short sh = f2bf(g2), sl = f2bf(g2 - bf2f(sh));
        uint4 h0, h1;
        h0.x = pk(hx, hy); h0.y = pk(hz, hx); h0.z = pk(hy, hz); h0.w = pk(lx, ly);
        h1.x = pk(lz, ONE); h1.y = pk(ONE, sh); h1.z = pk(sl, lx); h1.w = pk(ly, lz);
        Bf[i] = h0;
        Bf[NPTS + i] = h1;
    }
    minP[i] = 0x7F800000u;   // +inf
    minG[i] = 0x7F800000u;
}

__device__ inline float tree16(const f32x16 a) {   // min of 16 (v_min3 tree)
    float m0 = fminf(fminf(a[0],  a[1]),  a[2]);
    float m1 = fminf(fminf(a[3],  a[4]),  a[5]);
    float m2 = fminf(fminf(a[6],  a[7]),  a[8]);
    float m3 = fminf(fminf(a[9],  a[10]), a[11]);
    float m4 = fminf(fminf(a[12], a[13]), a[14]);
    float m5 = fminf(fminf(m0, m1), m2);
    float m6 = fminf(fminf(m3, m4), a[15]);
    return fminf(m5, m6);
}

// ---------------------------------------------------------------------------
// Main kernel: grid (32,32); block tile 512 rows x 512 cols, 4 waves.
// Wave w owns rows [w*128, w*128+128), one 32-row A-tile at a time.
// C/D layout (HW-verified): col = lane&31, row = (reg&3)+8*(reg>>2)+4*(lane>>5).
// B slice staged in LDS (16 KB); inner loop = ds_read_b128, fully unrolled.
// ---------------------------------------------------------------------------
__global__ __launch_bounds__(BLOCK, 2) void chamfer_mfma_kernel(
    const uint4* __restrict__ Af, const uint4* __restrict__ Bf,
    unsigned int* __restrict__ minP, unsigned int* __restrict__ minG,
    const float* __restrict__ wpred, const float* __restrict__ wgt,
    unsigned int* __restrict__ ticket, float* __restrict__ out)
{
    const int tid  = threadIdx.x;
    const int wv   = tid >> 6;
    const int lane = tid & 63;
    const int half = lane >> 5;
    const int ln31 = lane & 31;

    const int rowBase = blockIdx.x * ROWS_PER_BLOCK + wv * ROWS_PER_WAVE;
    const int colBase = blockIdx.y * COLS_PER_BLOCK;

    __shared__ uint4 sBf[2 * COLS_PER_BLOCK];      // 16 KB: [half][col]
    __shared__ unsigned int cminS[COLS_PER_BLOCK]; // 2 KB

    // Stage the block's B slice (both halves) + init col-min array.
    #pragma unroll
    for (int p = 0; p < (2 * COLS_PER_BLOCK) / BLOCK; ++p) {
        int idx = p * BLOCK + tid;
        int h = idx >> 9;           // /COLS_PER_BLOCK
        int c = idx & (COLS_PER_BLOCK - 1);
        sBf[idx] = Bf[h * NPTS + colBase + c];
    }
    for (int c = tid; c < COLS_PER_BLOCK; c += BLOCK)
        cminS[c] = 0x7F800000u;
    __syncthreads();

    const uint4* __restrict__ Ah = Af + half * NPTS;
    const uint4* sB = sBf + half * COLS_PER_BLOCK;   // this lane's k-half

    const f32x16 zacc = {0.f,0.f,0.f,0.f, 0.f,0.f,0.f,0.f,
                         0.f,0.f,0.f,0.f, 0.f,0.f,0.f,0.f};

    #pragma unroll 1
    for (int a = 0; a < ATILES; ++a) {
        uint4 ac = Ah[rowBase + a * 32 + ln31];
        bf16x8 af = __builtin_bit_cast(bf16x8, ac);

        float rm[16];
        #pragma unroll
        for (int r = 0; r < 16; ++r) rm[r] = INFINITY;

        #pragma unroll
        for (int s = 0; s < CSTEPS; ++s) {
            bf16x8 b0 = __builtin_bit_cast(bf16x8, sB[s * 64 + ln31]);
            bf16x8 b1 = __builtin_bit_cast(bf16x8, sB[s * 64 + 32 + ln31]);
            f32x16 acc0 = __builtin_amdgcn_mfma_f32_32x32x16_bf16(af, b0, zacc, 0, 0, 0);
            f32x16 acc1 = __builtin_amdgcn_mfma_f32_32x32x16_bf16(af, b1, zacc, 0, 0, 0);
            #pragma unroll
            for (int r = 0; r < 16; ++r)
                rm[r] = fminf(rm[r], fminf(acc0[r], acc1[r]));   // v_min3
            // Column mins for this A-tile: tree over 16 rows, combine halves.
            float c0 = fmaxf(tree16(acc0), 0.0f);
            float c1 = fmaxf(tree16(acc1), 0.0f);
            c0 = fminf(c0, __shfl_xor(c0, 32, 64));
            c1 = fminf(c1, __shfl_xor(c1, 32, 64));
            if (half == 0) {
                atomicMin(&cminS[s * 64 + ln31],      __float_as_uint(c0));
                atomicMin(&cminS[s * 64 + 32 + ln31], __float_as_uint(c1));
            }
        }

        // Row mins: butterfly over the 32 col-lanes.
        #pragma unroll
        for (int s = 1; s < 32; s <<= 1) {
            #pragma unroll
            for (int r = 0; r < 16; ++r)
                rm[r] = fminf(rm[r], __shfl_xor(rm[r], s, 64));
        }
        const int rb = rowBase + a * 32 + 4 * half;
        #pragma unroll
        for (int r = 0; r < 16; ++r) {
            if (ln31 == r)
                atomicMin(&minP[rb + (r & 3) + 8 * (r >> 2)],
                          __float_as_uint(fmaxf(rm[r], 0.0f)));
        }
    }

    __syncthreads();
    for (int c = tid; c < COLS_PER_BLOCK; c += BLOCK)
        atomicMin(&minG[colBase + c], cminS[c]);   // already clamped >= 0

    // ------------------- ticket: last block finalizes -----------------------
    __shared__ unsigned int sTicket;
    __syncthreads();
    __threadfence();
    if (tid == 0) sTicket = atomicAdd(ticket, 1u);
    __syncthreads();
    if (sTicket != (unsigned)(NBLOCKS - 1)) return;
    __threadfence();

    // Read via identity atomics (coherent across XCDs), weighted sums.
    float np = 0.f, dp = 0.f, ng = 0.f, dg = 0.f;
    for (int i = tid; i < NPTS; i += BLOCK) {
        float v = __uint_as_float(atomicMin(&minP[i], 0xFFFFFFFFu));
        float w = wpred[i];
        np = fmaf(w, v, np); dp += w;
        float u = __uint_as_float(atomicMin(&minG[i], 0xFFFFFFFFu));
        float x = wgt[i];
        ng = fmaf(x, u, ng); dg += x;
    }
    #pragma unroll
    for (int off = 1; off < 64; off <<= 1) {
        np += __shfl_xor(np, off, 64);
        dp += __shfl_xor(dp, off, 64);
        ng += __shfl_xor(ng, off, 64);
        dg += __shfl_xor(dg, off, 64);
    }
    __shared__ float sred[4][WAVES];
    if (lane == 0) { sred[0][wv] = np; sred[1][wv] = dp;
                     sred[2][wv] = ng; sred[3][wv] = dg; }
    __syncthreads();
    if (tid == 0) {
        float NP = 0.f, DP = 0.f, NG = 0.f, DG = 0.f;
        #pragma unroll
        for (int k = 0; k < WAVES; ++k) {
            NP += sred[0][k]; DP += sred[1][k];
            NG += sred[2][k]; DG += sred[3][k];
        }
        out[0] = NP / fmaxf(DP, 1e-9f) + NG / fmaxf(DG, 1e-9f);
    }
}

// ---------------------------------------------------------------------------
extern "C" void kernel_launch(void* const* d_in, const int* in_sizes, int n_in,
                              void* d_out, int out_size, void* d_ws, size_t ws_size,
                              hipStream_t stream)
{
    const float* pred  = (const float*)d_in[0];   // (P,3)
    const float* gt    = (const float*)d_in[1];   // (G,3)
    const float* wpred = (const float*)d_in[2];   // (P,)
    const float* wgt   = (const float*)d_in[3];   // (G,)
    float* out = (float*)d_out;

    // ws: Af(512K) | Bf(512K) | minP(64K) | minG(64K) | ticket  (~1.13 MB)
    uint4* Af = (uint4*)d_ws;
    uint4* Bf = Af + 2 * NPTS;
    unsigned int* minP = (unsigned int*)(Bf + 2 * NPTS);
    unsigned int* minG = minP + NPTS;
    unsigned int* ticket = minG + NPTS;

    pack_init_kernel<<<NPTS / BLOCK, BLOCK, 0, stream>>>(
        pred, gt, Af, Bf, minP, minG, ticket);

    chamfer_mfma_kernel<<<dim3(NBX, NBY), BLOCK, 0, stream>>>(
        Af, Bf, minP, minG, wpred, wgt, ticket, out);
}

// Round 7
// 212.696 us; speedup vs baseline: 1.5186x; 1.5186x over previous
//
#include <hip/hip_runtime.h>
#include <math.h>

// ---------------------------------------------------------------------------
// Chamfer distance via MFMA (gfx950) — round 7.
//
// d2(p,g) = p^2 + g^2 - 2 p.g computed entirely inside
// v_mfma_f32_32x32x16_bf16 via bf16 hi/lo (Dekker) split over K=16 slots
// (HW-verified absmax 0.0, rounds 1-6).
//
// Codegen law (3x confirmed: r3 launch_bounds, r4 prefetch, r6 full unroll):
// only r2's unroll-2 loop shape stays at ~60 VGPR; any perturbation spills
// (deterministic 60-270 MB WRITE_SIZE). This round keeps r2's EXACT loop
// shape and reductions, and changes only:
//   1. B slice read from LDS (staged once/block) -> ~120cy latency, no L1
//      thrash, no per-step address VALU.
//   2. BLOCK 256 -> 512 (8 waves), grid stays (32,32)=1024 -> 4 blocks/CU
//      x 8 waves = 32 waves/CU resident (r2 had 16 max), amortizing per-
//      block staging/epilogue over 2x waves.
// Tripwire: VGPR <= 72, WRITE_SIZE <= 8 MB, else spill returned.
// ---------------------------------------------------------------------------

constexpr int NPTS  = 16384;
constexpr int BLOCK = 512;                        // 8 waves
constexpr int WAVES = BLOCK / 64;

constexpr int ROWS_PER_BLOCK = 512;
constexpr int COLS_PER_BLOCK = 512;
constexpr int NBX = NPTS / ROWS_PER_BLOCK;        // 32
constexpr int NBY = NPTS / COLS_PER_BLOCK;        // 32
constexpr int NBLOCKS = NBX * NBY;                // 1024
constexpr int ROWS_PER_WAVE = ROWS_PER_BLOCK / WAVES;   // 64
constexpr int ATILES = ROWS_PER_WAVE / 32;        // 2
constexpr int CSTEPS = COLS_PER_BLOCK / 64;       // 8 (two 32-col tiles/step)

typedef __attribute__((ext_vector_type(8)))  __bf16 bf16x8;
typedef __attribute__((ext_vector_type(16))) float  f32x16;

__device__ inline unsigned short f2bf(float f) {          // RNE float->bf16
    unsigned u = __float_as_uint(f);
    u += 0x7FFFu + ((u >> 16) & 1u);
    return (unsigned short)(u >> 16);
}
__device__ inline float bf2f(unsigned short h) {
    return __uint_as_float(((unsigned)h) << 16);
}
__device__ inline unsigned pk(unsigned short lo, unsigned short hi) {
    return (unsigned)lo | ((unsigned)hi << 16);
}

// ---------------------------------------------------------------------------
// Pack to FRAG-READY layout: per point two uint4s (one per k-half), each the
// exact 8-bf16 MFMA fragment for that half (verified layout, rounds 1-6):
//   A half0: [phx,phy,phz, plx,ply,plz, phx,phy]
//   A half1: [phz, p2h, p2l, 1, 1, plx, ply, plz]
//   B half0: [mhx,mhy,mhz, mhx,mhy,mhz, mlx,mly]      (m = -2g)
//   B half1: [mlz, 1, 1, g2h, g2l, mlx, mly, mlz]
// Array layout: half-major — Xf[half*NPTS + i].
// ---------------------------------------------------------------------------
__global__ __launch_bounds__(256) void pack_init_kernel(
    const float* __restrict__ pred, const float* __restrict__ gt,
    uint4* __restrict__ Af, uint4* __restrict__ Bf,
    unsigned int* __restrict__ minP, unsigned int* __restrict__ minG,
    unsigned int* __restrict__ ticket)
{
    const unsigned short ONE = 0x3F80;
    int i = blockIdx.x * 256 + threadIdx.x;
    if (i == 0) *ticket = 0u;
    if (i >= NPTS) return;

    {   // A side (pred)
        float x = pred[3*i], y = pred[3*i+1], z = pred[3*i+2];
        unsigned short hx = f2bf(x), hy = f2bf(y), hz = f2bf(z);
        unsigned short lx = f2bf(x - bf2f(hx));
        unsigned short ly = f2bf(y - bf2f(hy));
        unsigned short lz = f2bf(z - bf2f(hz));
        float p2 = fmaf(x, x, fmaf(y, y, z * z));
        unsigned short sh = f2bf(p2), sl = f2bf(p2 - bf2f(sh));
        uint4 h0, h1;
        h0.x = pk(hx, hy); h0.y = pk(hz, lx); h0.z = pk(ly, lz); h0.w = pk(hx, hy);
        h1.x = pk(hz, sh); h1.y = pk(sl, ONE); h1.z = pk(ONE, lx); h1.w = pk(ly, lz);
        Af[i] = h0;
        Af[NPTS + i] = h1;
    }
    {   // B side (gt, pre-scaled by -2)
        float gx = gt[3*i], gy = gt[3*i+1], gz = gt[3*i+2];
        float mx = -2.0f * gx, my = -2.0f * gy, mz = -2.0f * gz;
        unsigned short hx = f2bf(mx), hy = f2bf(my), hz = f2bf(mz);
        unsigned short lx = f2bf(mx - bf2f(hx));
        unsigned short ly = f2bf(my - bf2f(hy));
        unsigned short lz = f2bf(mz - bf2f(hz));
        float g2 = fmaf(gx, gx, fmaf(gy, gy, gz * gz));
        unsigned short sh = f2bf(g2), sl = f2bf(g2 - bf2f(sh));
        uint4 h0, h1;
        h0.x = pk(hx, hy); h0.y = pk(hz, hx); h0.z = pk(hy, hz); h0.w = pk(lx, ly);
        h1.x = pk(lz, ONE); h1.y = pk(ONE, sh); h1.z = pk(sl, lx); h1.w = pk(ly, lz);
        Bf[i] = h0;
        Bf[NPTS + i] = h1;
    }
    minP[i] = 0x7F800000u;   // +inf
    minG[i] = 0x7F800000u;
}

__device__ inline float tree16(const f32x16 a) {   // min of 16 (v_min3 tree)
    float m0 = fminf(fminf(a[0],  a[1]),  a[2]);
    float m1 = fminf(fminf(a[3],  a[4]),  a[5]);
    float m2 = fminf(fminf(a[6],  a[7]),  a[8]);
    float m3 = fminf(fminf(a[9],  a[10]), a[11]);
    float m4 = fminf(fminf(a[12], a[13]), a[14]);
    float m5 = fminf(fminf(m0, m1), m2);
    float m6 = fminf(fminf(m3, m4), a[15]);
    return fminf(m5, m6);
}

// ---------------------------------------------------------------------------
// Main kernel: grid (32,32); block tile 512 rows x 512 cols, 8 waves.
// Wave w owns rows [w*64, w*64+64), one 32-row A-tile at a time.
// C/D layout (HW-verified): col = lane&31, row = (reg&3)+8*(reg>>2)+4*(lane>>5).
// B slice staged in LDS (16 KB); inner loop shape byte-identical to r2
// (unroll 2, same reductions) with ds_read instead of global load.
// ---------------------------------------------------------------------------
__global__ __launch_bounds__(BLOCK, 2) void chamfer_mfma_kernel(
    const uint4* __restrict__ Af, const uint4* __restrict__ Bf,
    unsigned int* __restrict__ minP, unsigned int* __restrict__ minG,
    const float* __restrict__ wpred, const float* __restrict__ wgt,
    unsigned int* __restrict__ ticket, float* __restrict__ out)
{
    const int tid  = threadIdx.x;
    const int wv   = tid >> 6;
    const int lane = tid & 63;
    const int half = lane >> 5;
    const int ln31 = lane & 31;

    const int rowBase = blockIdx.x * ROWS_PER_BLOCK + wv * ROWS_PER_WAVE;
    const int colBase = blockIdx.y * COLS_PER_BLOCK;

    __shared__ uint4 sBf[2 * COLS_PER_BLOCK];      // 16 KB: [half][col]
    __shared__ unsigned int cminS[COLS_PER_BLOCK]; // 2 KB

    // Stage the block's B slice (both halves) + init col-min array.
    #pragma unroll
    for (int p = 0; p < (2 * COLS_PER_BLOCK) / BLOCK; ++p) {
        int idx = p * BLOCK + tid;
        int h = idx >> 9;           // /COLS_PER_BLOCK
        int c = idx & (COLS_PER_BLOCK - 1);
        sBf[idx] = Bf[h * NPTS + colBase + c];
    }
    for (int c = tid; c < COLS_PER_BLOCK; c += BLOCK)
        cminS[c] = 0x7F800000u;
    __syncthreads();

    const uint4* __restrict__ Ah = Af + half * NPTS;
    const uint4* sB = sBf + half * COLS_PER_BLOCK;   // this lane's k-half

    const f32x16 zacc = {0.f,0.f,0.f,0.f, 0.f,0.f,0.f,0.f,
                         0.f,0.f,0.f,0.f, 0.f,0.f,0.f,0.f};

    #pragma unroll 1
    for (int a = 0; a < ATILES; ++a) {
        uint4 ac = Ah[rowBase + a * 32 + ln31];
        bf16x8 af = __builtin_bit_cast(bf16x8, ac);

        float rm[16];
        #pragma unroll
        for (int r = 0; r < 16; ++r) rm[r] = INFINITY;

        #pragma unroll 2
        for (int s = 0; s < CSTEPS; ++s) {
            bf16x8 b0 = __builtin_bit_cast(bf16x8, sB[s * 64 + ln31]);
            bf16x8 b1 = __builtin_bit_cast(bf16x8, sB[s * 64 + 32 + ln31]);
            f32x16 acc0 = __builtin_amdgcn_mfma_f32_32x32x16_bf16(af, b0, zacc, 0, 0, 0);
            f32x16 acc1 = __builtin_amdgcn_mfma_f32_32x32x16_bf16(af, b1, zacc, 0, 0, 0);
            #pragma unroll
            for (int r = 0; r < 16; ++r)
                rm[r] = fminf(rm[r], fminf(acc0[r], acc1[r]));   // v_min3
            // Column mins for this A-tile: tree over 16 rows, combine halves.
            float c0 = fmaxf(tree16(acc0), 0.0f);
            float c1 = fmaxf(tree16(acc1), 0.0f);
            c0 = fminf(c0, __shfl_xor(c0, 32, 64));
            c1 = fminf(c1, __shfl_xor(c1, 32, 64));
            if (half == 0) {
                atomicMin(&cminS[s * 64 + ln31],      __float_as_uint(c0));
                atomicMin(&cminS[s * 64 + 32 + ln31], __float_as_uint(c1));
            }
        }

        // Row mins: butterfly over the 32 col-lanes.
        #pragma unroll
        for (int s = 1; s < 32; s <<= 1) {
            #pragma unroll
            for (int r = 0; r < 16; ++r)
                rm[r] = fminf(rm[r], __shfl_xor(rm[r], s, 64));
        }
        const int rb = rowBase + a * 32 + 4 * half;
        #pragma unroll
        for (int r = 0; r < 16; ++r) {
            if (ln31 == r)
                atomicMin(&minP[rb + (r & 3) + 8 * (r >> 2)],
                          __float_as_uint(fmaxf(rm[r], 0.0f)));
        }
    }

    __syncthreads();
    for (int c = tid; c < COLS_PER_BLOCK; c += BLOCK)
        atomicMin(&minG[colBase + c], cminS[c]);   // already clamped >= 0

    // ------------------- ticket: last block finalizes -----------------------
    __shared__ unsigned int sTicket;
    __syncthreads();
    __threadfence();
    if (tid == 0) sTicket = atomicAdd(ticket, 1u);
    __syncthreads();
    if (sTicket != (unsigned)(NBLOCKS - 1)) return;
    __threadfence();

    // Read via identity atomics (coherent across XCDs), weighted sums.
    float np = 0.f, dp = 0.f, ng = 0.f, dg = 0.f;
    for (int i = tid; i < NPTS; i += BLOCK) {
        float v = __uint_as_float(atomicMin(&minP[i], 0xFFFFFFFFu));
        float w = wpred[i];
        np = fmaf(w, v, np); dp += w;
        float u = __uint_as_float(atomicMin(&minG[i], 0xFFFFFFFFu));
        float x = wgt[i];
        ng = fmaf(x, u, ng); dg += x;
    }
    #pragma unroll
    for (int off = 1; off < 64; off <<= 1) {
        np += __shfl_xor(np, off, 64);
        dp += __shfl_xor(dp, off, 64);
        ng += __shfl_xor(ng, off, 64);
        dg += __shfl_xor(dg, off, 64);
    }
    __shared__ float sred[4][WAVES];
    if (lane == 0) { sred[0][wv] = np; sred[1][wv] = dp;
                     sred[2][wv] = ng; sred[3][wv] = dg; }
    __syncthreads();
    if (tid == 0) {
        float NP = 0.f, DP = 0.f, NG = 0.f, DG = 0.f;
        #pragma unroll
        for (int k = 0; k < WAVES; ++k) {
            NP += sred[0][k]; DP += sred[1][k];
            NG += sred[2][k]; DG += sred[3][k];
        }
        out[0] = NP / fmaxf(DP, 1e-9f) + NG / fmaxf(DG, 1e-9f);
    }
}

// ---------------------------------------------------------------------------
extern "C" void kernel_launch(void* const* d_in, const int* in_sizes, int n_in,
                              void* d_out, int out_size, void* d_ws, size_t ws_size,
                              hipStream_t stream)
{
    const float* pred  = (const float*)d_in[0];   // (P,3)
    const float* gt    = (const float*)d_in[1];   // (G,3)
    const float* wpred = (const float*)d_in[2];   // (P,)
    const float* wgt   = (const float*)d_in[3];   // (G,)
    float* out = (float*)d_out;

    // ws: Af(512K) | Bf(512K) | minP(64K) | minG(64K) | ticket  (~1.13 MB)
    uint4* Af = (uint4*)d_ws;
    uint4* Bf = Af + 2 * NPTS;
    unsigned int* minP = (unsigned int*)(Bf + 2 * NPTS);
    unsigned int* minG = minP + NPTS;
    unsigned int* ticket = minG + NPTS;

    pack_init_kernel<<<NPTS / 256, 256, 0, stream>>>(
        pred, gt, Af, Bf, minP, minG, ticket);

    chamfer_mfma_kernel<<<dim3(NBX, NBY), BLOCK, 0, stream>>>(
        Af, Bf, minP, minG, wpred, wgt, ticket, out);
}

// Round 8
// 107.985 us; speedup vs baseline: 2.9911x; 1.9697x over previous
//
#include <hip/hip_runtime.h>
#include <math.h>

// ---------------------------------------------------------------------------
// Chamfer distance via MFMA (gfx950) — round 8.
//
// d2(p,g) = p^2 + g^2 - 2 p.g computed entirely inside
// v_mfma_f32_32x32x16_bf16 via bf16 hi/lo (Dekker) split over K=16 slots
// (HW-verified absmax 0.0, rounds 1-7).
//
// Fence-tax theory (fit across r2/r5/r7): wall time tracks 2 x NBLOCKS x
// __threadfence() (device-scope release = cross-XCD L2 writeback, ~50ns
// serialized each), not loop structure: 2048 fences + 25us issue = 123us
// (r2 measured 123); 4096 -> 172 (r5); r7 = 161. This round: r7 byte-
// identical EXCEPT the two __threadfence() are removed. Correctness: all
// cross-block traffic (minP/minG, ticket, final re-reads) is device-scope
// atomics resolving at the coherent point; the only required ordering is
// completion of this block's atomics before the ticket bump, provided by
// explicit s_waitcnt vmcnt(0) + __syncthreads().
// Tripwires: VGPR ~56, WRITE ~4 MB, FETCH ~2.5 MB.
// ---------------------------------------------------------------------------

constexpr int NPTS  = 16384;
constexpr int BLOCK = 512;                        // 8 waves
constexpr int WAVES = BLOCK / 64;

constexpr int ROWS_PER_BLOCK = 512;
constexpr int COLS_PER_BLOCK = 512;
constexpr int NBX = NPTS / ROWS_PER_BLOCK;        // 32
constexpr int NBY = NPTS / COLS_PER_BLOCK;        // 32
constexpr int NBLOCKS = NBX * NBY;                // 1024
constexpr int ROWS_PER_WAVE = ROWS_PER_BLOCK / WAVES;   // 64
constexpr int ATILES = ROWS_PER_WAVE / 32;        // 2
constexpr int CSTEPS = COLS_PER_BLOCK / 64;       // 8 (two 32-col tiles/step)

typedef __attribute__((ext_vector_type(8)))  __bf16 bf16x8;
typedef __attribute__((ext_vector_type(16))) float  f32x16;

__device__ inline unsigned short f2bf(float f) {          // RNE float->bf16
    unsigned u = __float_as_uint(f);
    u += 0x7FFFu + ((u >> 16) & 1u);
    return (unsigned short)(u >> 16);
}
__device__ inline float bf2f(unsigned short h) {
    return __uint_as_float(((unsigned)h) << 16);
}
__device__ inline unsigned pk(unsigned short lo, unsigned short hi) {
    return (unsigned)lo | ((unsigned)hi << 16);
}

// ---------------------------------------------------------------------------
// Pack to FRAG-READY layout: per point two uint4s (one per k-half), each the
// exact 8-bf16 MFMA fragment for that half (verified layout, rounds 1-7):
//   A half0: [phx,phy,phz, plx,ply,plz, phx,phy]
//   A half1: [phz, p2h, p2l, 1, 1, plx, ply, plz]
//   B half0: [mhx,mhy,mhz, mhx,mhy,mhz, mlx,mly]      (m = -2g)
//   B half1: [mlz, 1, 1, g2h, g2l, mlx, mly, mlz]
// Array layout: half-major — Xf[half*NPTS + i].
// ---------------------------------------------------------------------------
__global__ __launch_bounds__(256) void pack_init_kernel(
    const float* __restrict__ pred, const float* __restrict__ gt,
    uint4* __restrict__ Af, uint4* __restrict__ Bf,
    unsigned int* __restrict__ minP, unsigned int* __restrict__ minG,
    unsigned int* __restrict__ ticket)
{
    const unsigned short ONE = 0x3F80;
    int i = blockIdx.x * 256 + threadIdx.x;
    if (i == 0) *ticket = 0u;
    if (i >= NPTS) return;

    {   // A side (pred)
        float x = pred[3*i], y = pred[3*i+1], z = pred[3*i+2];
        unsigned short hx = f2bf(x), hy = f2bf(y), hz = f2bf(z);
        unsigned short lx = f2bf(x - bf2f(hx));
        unsigned short ly = f2bf(y - bf2f(hy));
        unsigned short lz = f2bf(z - bf2f(hz));
        float p2 = fmaf(x, x, fmaf(y, y, z * z));
        unsigned short sh = f2bf(p2), sl = f2bf(p2 - bf2f(sh));
        uint4 h0, h1;
        h0.x = pk(hx, hy); h0.y = pk(hz, lx); h0.z = pk(ly, lz); h0.w = pk(hx, hy);
        h1.x = pk(hz, sh); h1.y = pk(sl, ONE); h1.z = pk(ONE, lx); h1.w = pk(ly, lz);
        Af[i] = h0;
        Af[NPTS + i] = h1;
    }
    {   // B side (gt, pre-scaled by -2)
        float gx = gt[3*i], gy = gt[3*i+1], gz = gt[3*i+2];
        float mx = -2.0f * gx, my = -2.0f * gy, mz = -2.0f * gz;
        unsigned short hx = f2bf(mx), hy = f2bf(my), hz = f2bf(mz);
        unsigned short lx = f2bf(mx - bf2f(hx));
        unsigned short ly = f2bf(my - bf2f(hy));
        unsigned short lz = f2bf(mz - bf2f(hz));
        float g2 = fmaf(gx, gx, fmaf(gy, gy, gz * gz));
        unsigned short sh = f2bf(g2), sl = f2bf(g2 - bf2f(sh));
        uint4 h0, h1;
        h0.x = pk(hx, hy); h0.y = pk(hz, hx); h0.z = pk(hy, hz); h0.w = pk(lx, ly);
        h1.x = pk(lz, ONE); h1.y = pk(ONE, sh); h1.z = pk(sl, lx); h1.w = pk(ly, lz);
        Bf[i] = h0;
        Bf[NPTS + i] = h1;
    }
    minP[i] = 0x7F800000u;   // +inf
    minG[i] = 0x7F800000u;
}

__device__ inline float tree16(const f32x16 a) {   // min of 16 (v_min3 tree)
    float m0 = fminf(fminf(a[0],  a[1]),  a[2]);
    float m1 = fminf(fminf(a[3],  a[4]),  a[5]);
    float m2 = fminf(fminf(a[6],  a[7]),  a[8]);
    float m3 = fminf(fminf(a[9],  a[10]), a[11]);
    float m4 = fminf(fminf(a[12], a[13]), a[14]);
    float m5 = fminf(fminf(m0, m1), m2);
    float m6 = fminf(fminf(m3, m4), a[15]);
    return fminf(m5, m6);
}

// ---------------------------------------------------------------------------
// Main kernel: grid (32,32); block tile 512 rows x 512 cols, 8 waves.
// Wave w owns rows [w*64, w*64+64), one 32-row A-tile at a time.
// C/D layout (HW-verified): col = lane&31, row = (reg&3)+8*(reg>>2)+4*(lane>>5).
// B slice staged in LDS (16 KB); loop shape identical to r7 (= r2's verified
// spill-free codegen). NO __threadfence anywhere.
// ---------------------------------------------------------------------------
__global__ __launch_bounds__(BLOCK, 2) void chamfer_mfma_kernel(
    const uint4* __restrict__ Af, const uint4* __restrict__ Bf,
    unsigned int* __restrict__ minP, unsigned int* __restrict__ minG,
    const float* __restrict__ wpred, const float* __restrict__ wgt,
    unsigned int* __restrict__ ticket, float* __restrict__ out)
{
    const int tid  = threadIdx.x;
    const int wv   = tid >> 6;
    const int lane = tid & 63;
    const int half = lane >> 5;
    const int ln31 = lane & 31;

    const int rowBase = blockIdx.x * ROWS_PER_BLOCK + wv * ROWS_PER_WAVE;
    const int colBase = blockIdx.y * COLS_PER_BLOCK;

    __shared__ uint4 sBf[2 * COLS_PER_BLOCK];      // 16 KB: [half][col]
    __shared__ unsigned int cminS[COLS_PER_BLOCK]; // 2 KB

    // Stage the block's B slice (both halves) + init col-min array.
    #pragma unroll
    for (int p = 0; p < (2 * COLS_PER_BLOCK) / BLOCK; ++p) {
        int idx = p * BLOCK + tid;
        int h = idx >> 9;           // /COLS_PER_BLOCK
        int c = idx & (COLS_PER_BLOCK - 1);
        sBf[idx] = Bf[h * NPTS + colBase + c];
    }
    for (int c = tid; c < COLS_PER_BLOCK; c += BLOCK)
        cminS[c] = 0x7F800000u;
    __syncthreads();

    const uint4* __restrict__ Ah = Af + half * NPTS;
    const uint4* sB = sBf + half * COLS_PER_BLOCK;   // this lane's k-half

    const f32x16 zacc = {0.f,0.f,0.f,0.f, 0.f,0.f,0.f,0.f,
                         0.f,0.f,0.f,0.f, 0.f,0.f,0.f,0.f};

    #pragma unroll 1
    for (int a = 0; a < ATILES; ++a) {
        uint4 ac = Ah[rowBase + a * 32 + ln31];
        bf16x8 af = __builtin_bit_cast(bf16x8, ac);

        float rm[16];
        #pragma unroll
        for (int r = 0; r < 16; ++r) rm[r] = INFINITY;

        #pragma unroll 2
        for (int s = 0; s < CSTEPS; ++s) {
            bf16x8 b0 = __builtin_bit_cast(bf16x8, sB[s * 64 + ln31]);
            bf16x8 b1 = __builtin_bit_cast(bf16x8, sB[s * 64 + 32 + ln31]);
            f32x16 acc0 = __builtin_amdgcn_mfma_f32_32x32x16_bf16(af, b0, zacc, 0, 0, 0);
            f32x16 acc1 = __builtin_amdgcn_mfma_f32_32x32x16_bf16(af, b1, zacc, 0, 0, 0);
            #pragma unroll
            for (int r = 0; r < 16; ++r)
                rm[r] = fminf(rm[r], fminf(acc0[r], acc1[r]));   // v_min3
            // Column mins for this A-tile: tree over 16 rows, combine halves.
            float c0 = fmaxf(tree16(acc0), 0.0f);
            float c1 = fmaxf(tree16(acc1), 0.0f);
            c0 = fminf(c0, __shfl_xor(c0, 32, 64));
            c1 = fminf(c1, __shfl_xor(c1, 32, 64));
            if (half == 0) {
                atomicMin(&cminS[s * 64 + ln31],      __float_as_uint(c0));
                atomicMin(&cminS[s * 64 + 32 + ln31], __float_as_uint(c1));
            }
        }

        // Row mins: butterfly over the 32 col-lanes.
        #pragma unroll
        for (int s = 1; s < 32; s <<= 1) {
            #pragma unroll
            for (int r = 0; r < 16; ++r)
                rm[r] = fminf(rm[r], __shfl_xor(rm[r], s, 64));
        }
        const int rb = rowBase + a * 32 + 4 * half;
        #pragma unroll
        for (int r = 0; r < 16; ++r) {
            if (ln31 == r)
                atomicMin(&minP[rb + (r & 3) + 8 * (r >> 2)],
                          __float_as_uint(fmaxf(rm[r], 0.0f)));
        }
    }

    __syncthreads();
    for (int c = tid; c < COLS_PER_BLOCK; c += BLOCK)
        atomicMin(&minG[colBase + c], cminS[c]);   // already clamped >= 0

    // ------------------- ticket: last block finalizes -----------------------
    // All cross-block data flows through device-scope atomics (coherent point)
    // so no __threadfence (cross-XCD L2 writeback) is needed — only completion
    // of this thread's atomics (s_waitcnt vmcnt(0)) before signaling.
    __shared__ unsigned int sTicket;
    asm volatile("s_waitcnt vmcnt(0)" ::: "memory");
    __syncthreads();
    if (tid == 0) sTicket = atomicAdd(ticket, 1u);
    __syncthreads();
    if (sTicket != (unsigned)(NBLOCKS - 1)) return;

    // Read via identity atomics (coherent across XCDs), weighted sums.
    float np = 0.f, dp = 0.f, ng = 0.f, dg = 0.f;
    for (int i = tid; i < NPTS; i += BLOCK) {
        float v = __uint_as_float(atomicMin(&minP[i], 0xFFFFFFFFu));
        float w = wpred[i];
        np = fmaf(w, v, np); dp += w;
        float u = __uint_as_float(atomicMin(&minG[i], 0xFFFFFFFFu));
        float x = wgt[i];
        ng = fmaf(x, u, ng); dg += x;
    }
    #pragma unroll
    for (int off = 1; off < 64; off <<= 1) {
        np += __shfl_xor(np, off, 64);
        dp += __shfl_xor(dp, off, 64);
        ng += __shfl_xor(ng, off, 64);
        dg += __shfl_xor(dg, off, 64);
    }
    __shared__ float sred[4][WAVES];
    if (lane == 0) { sred[0][wv] = np; sred[1][wv] = dp;
                     sred[2][wv] = ng; sred[3][wv] = dg; }
    __syncthreads();
    if (tid == 0) {
        float NP = 0.f, DP = 0.f, NG = 0.f, DG = 0.f;
        #pragma unroll
        for (int k = 0; k < WAVES; ++k) {
            NP += sred[0][k]; DP += sred[1][k];
            NG += sred[2][k]; DG += sred[3][k];
        }
        out[0] = NP / fmaxf(DP, 1e-9f) + NG / fmaxf(DG, 1e-9f);
    }
}

// ---------------------------------------------------------------------------
extern "C" void kernel_launch(void* const* d_in, const int* in_sizes, int n_in,
                              void* d_out, int out_size, void* d_ws, size_t ws_size,
                              hipStream_t stream)
{
    const float* pred  = (const float*)d_in[0];   // (P,3)
    const float* gt    = (const float*)d_in[1];   // (G,3)
    const float* wpred = (const float*)d_in[2];   // (P,)
    const float* wgt   = (const float*)d_in[3];   // (G,)
    float* out = (float*)d_out;

    // ws: Af(512K) | Bf(512K) | minP(64K) | minG(64K) | ticket  (~1.13 MB)
    uint4* Af = (uint4*)d_ws;
    uint4* Bf = Af + 2 * NPTS;
    unsigned int* minP = (unsigned int*)(Bf + 2 * NPTS);
    unsigned int* minG = minP + NPTS;
    unsigned int* ticket = minG + NPTS;

    pack_init_kernel<<<NPTS / 256, 256, 0, stream>>>(
        pred, gt, Af, Bf, minP, minG, ticket);

    chamfer_mfma_kernel<<<dim3(NBX, NBY), BLOCK, 0, stream>>>(
        Af, Bf, minP, minG, wpred, wgt, ticket, out);
}

// Round 9
// 99.943 us; speedup vs baseline: 3.2318x; 1.0805x over previous
//
#include <hip/hip_runtime.h>
#include <math.h>

// ---------------------------------------------------------------------------
// Chamfer distance via MFMA (gfx950) — round 9: two symmetric passes.
//
// d2(p,g) = p^2 + g^2 - 2 p.g computed entirely inside
// v_mfma_f32_32x32x16_bf16 via bf16 hi/lo (Dekker) split over K=16 slots
// (HW-verified absmax 0.0, rounds 1-8). r8 removed the __threadfence tax
// (161 -> 59 us). Remaining cost was the row-min butterfly (80 shfl + 80 min
// per a-tile + rm[16] carried state). This round: MFMA is only 5.5% utilized,
// so run TWO passes with swapped operands (grid z), making the reduction
// lane-local in BOTH directions:
//   z=0: mfma(A=pred, B=gt)  -> lane holds gt col -> tree16 -> minG
//   z=1: mfma(A=gt,  B=pred) -> lane holds pred col -> tree16 -> minP
// No butterfly, no rm[], no guarded scatter. Pack emits 4 frag-ready arrays.
// Loop shape stays r2/r7's verified spill-free codegen (unroll 2).
// Tripwires: VGPR <= 56, WRITE <= 8 MB, FETCH <= 6 MB.
// ---------------------------------------------------------------------------

constexpr int NPTS  = 16384;
constexpr int BLOCK = 512;                        // 8 waves
constexpr int WAVES = BLOCK / 64;

constexpr int ROWS_PER_BLOCK = 512;
constexpr int COLS_PER_BLOCK = 512;
constexpr int NBX = NPTS / ROWS_PER_BLOCK;        // 32
constexpr int NBY = NPTS / COLS_PER_BLOCK;        // 32
constexpr int NBLOCKS = NBX * NBY * 2;            // 2048 (both passes)
constexpr int ROWS_PER_WAVE = ROWS_PER_BLOCK / WAVES;   // 64
constexpr int ATILES = ROWS_PER_WAVE / 32;        // 2
constexpr int CSTEPS = COLS_PER_BLOCK / 64;       // 8 (two 32-col tiles/step)

typedef __attribute__((ext_vector_type(8)))  __bf16 bf16x8;
typedef __attribute__((ext_vector_type(16))) float  f32x16;

__device__ inline unsigned short f2bf(float f) {          // RNE float->bf16
    unsigned u = __float_as_uint(f);
    u += 0x7FFFu + ((u >> 16) & 1u);
    return (unsigned short)(u >> 16);
}
__device__ inline float bf2f(unsigned short h) {
    return __uint_as_float(((unsigned)h) << 16);
}
__device__ inline unsigned pk(unsigned short lo, unsigned short hi) {
    return (unsigned)lo | ((unsigned)hi << 16);
}

// ---------------------------------------------------------------------------
// Fragment layouts (HW-verified pairing, rounds 1-8). For vector v with norm
// s (split hi/lo), slot sum of A(v,s) . B(w,t) = v.w + s + t:
//   A half0: [vhx,vhy,vhz, vlx,vly,vlz, vhx,vhy]
//   A half1: [vhz, s_h, s_l, 1, 1, vlx, vly, vlz]
//   B half0: [whx,why,whz, whx,why,whz, wlx,wly]
//   B half1: [wlz, 1, 1, t_h, t_l, wlx, wly, wlz]
// Pass 1: A(p,p2) . B(-2g,g2) = d2.  Pass 2: A(-2g,g2) . B(p,p2) = d2.
// Arrays (half-major, X[half*NPTS+i]):
//   Af = A-layout(p,p2)    Bf = B-layout(-2g,g2)
//   Ag = A-layout(-2g,g2)  Bp = B-layout(p,p2)
// ---------------------------------------------------------------------------
__global__ __launch_bounds__(256) void pack_init_kernel(
    const float* __restrict__ pred, const float* __restrict__ gt,
    uint4* __restrict__ Af, uint4* __restrict__ Bf,
    uint4* __restrict__ Ag, uint4* __restrict__ Bp,
    unsigned int* __restrict__ minP, unsigned int* __restrict__ minG,
    unsigned int* __restrict__ ticket)
{
    const unsigned short ONE = 0x3F80;
    int i = blockIdx.x * 256 + threadIdx.x;
    if (i == 0) *ticket = 0u;
    if (i >= NPTS) return;

    {   // pred: split p, p2
        float x = pred[3*i], y = pred[3*i+1], z = pred[3*i+2];
        unsigned short hx = f2bf(x), hy = f2bf(y), hz = f2bf(z);
        unsigned short lx = f2bf(x - bf2f(hx));
        unsigned short ly = f2bf(y - bf2f(hy));
        unsigned short lz = f2bf(z - bf2f(hz));
        float p2 = fmaf(x, x, fmaf(y, y, z * z));
        unsigned short sh = f2bf(p2), sl = f2bf(p2 - bf2f(sh));
        uint4 a0, a1, b0, b1;
        a0.x = pk(hx, hy); a0.y = pk(hz, lx); a0.z = pk(ly, lz); a0.w = pk(hx, hy);
        a1.x = pk(hz, sh); a1.y = pk(sl, ONE); a1.z = pk(ONE, lx); a1.w = pk(ly, lz);
        b0.x = pk(hx, hy); b0.y = pk(hz, hx); b0.z = pk(hy, hz); b0.w = pk(lx, ly);
        b1.x = pk(lz, ONE); b1.y = pk(ONE, sh); b1.z = pk(sl, lx); b1.w = pk(ly, lz);
        Af[i] = a0; Af[NPTS + i] = a1;
        Bp[i] = b0; Bp[NPTS + i] = b1;
    }
    {   // gt: split m = -2g, g2
        float gx = gt[3*i], gy = gt[3*i+1], gz = gt[3*i+2];
        float mx = -2.0f * gx, my = -2.0f * gy, mz = -2.0f * gz;
        unsigned short hx = f2bf(mx), hy = f2bf(my), hz = f2bf(mz);
        unsigned short lx = f2bf(mx - bf2f(hx));
        unsigned short ly = f2bf(my - bf2f(hy));
        unsigned short lz = f2bf(mz - bf2f(hz));
        float g2 = fmaf(gx, gx, fmaf(gy, gy, gz * gz));
        unsigned short sh = f2bf(g2), sl = f2bf(g2 - bf2f(sh));
        uint4 a0, a1, b0, b1;
        a0.x = pk(hx, hy); a0.y = pk(hz, lx); a0.z = pk(ly, lz); a0.w = pk(hx, hy);
        a1.x = pk(hz, sh); a1.y = pk(sl, ONE); a1.z = pk(ONE, lx); a1.w = pk(ly, lz);
        b0.x = pk(hx, hy); b0.y = pk(hz, hx); b0.z = pk(hy, hz); b0.w = pk(lx, ly);
        b1.x = pk(lz, ONE); b1.y = pk(ONE, sh); b1.z = pk(sl, lx); b1.w = pk(ly, lz);
        Ag[i] = a0; Ag[NPTS + i] = a1;
        Bf[i] = b0; Bf[NPTS + i] = b1;
    }
    minP[i] = 0x7F800000u;   // +inf
    minG[i] = 0x7F800000u;
}

__device__ inline float tree16(const f32x16 a) {   // min of 16 (v_min3 tree)
    float m0 = fminf(fminf(a[0],  a[1]),  a[2]);
    float m1 = fminf(fminf(a[3],  a[4]),  a[5]);
    float m2 = fminf(fminf(a[6],  a[7]),  a[8]);
    float m3 = fminf(fminf(a[9],  a[10]), a[11]);
    float m4 = fminf(fminf(a[12], a[13]), a[14]);
    float m5 = fminf(fminf(m0, m1), m2);
    float m6 = fminf(fminf(m3, m4), a[15]);
    return fminf(m5, m6);
}

// ---------------------------------------------------------------------------
// Main kernel: grid (32,32,2); block tile 512 A-rows x 512 B-cols, 8 waves.
// z picks the pass (which cloud is on the lane axis). Wave w owns A-rows
// [w*64, w*64+64). C/D layout (HW-verified): col = lane&31,
// row = (reg&3)+8*(reg>>2)+4*(lane>>5) -> per-lane tree16 = min over A-rows
// for this lane's B-col; halves/waves/a-tiles merge in cminS via LDS atomics;
// blocks merge via global atomicMin. No __threadfence (r8-verified protocol).
// ---------------------------------------------------------------------------
__global__ __launch_bounds__(BLOCK, 2) void chamfer_mfma_kernel(
    const uint4* __restrict__ Af, const uint4* __restrict__ Bf,
    const uint4* __restrict__ Ag, const uint4* __restrict__ Bp,
    unsigned int* __restrict__ minP, unsigned int* __restrict__ minG,
    const float* __restrict__ wpred, const float* __restrict__ wgt,
    unsigned int* __restrict__ ticket, float* __restrict__ out)
{
    const int tid  = threadIdx.x;
    const int wv   = tid >> 6;
    const int lane = tid & 63;
    const int half = lane >> 5;
    const int ln31 = lane & 31;

    const uint4* __restrict__ Aside;
    const uint4* __restrict__ Bside;
    unsigned int* __restrict__ outMin;
    if (blockIdx.z == 0) { Aside = Af; Bside = Bf; outMin = minG; }
    else                 { Aside = Ag; Bside = Bp; outMin = minP; }

    const int rowBase = blockIdx.x * ROWS_PER_BLOCK + wv * ROWS_PER_WAVE;
    const int colBase = blockIdx.y * COLS_PER_BLOCK;

    __shared__ uint4 sBf[2 * COLS_PER_BLOCK];      // 16 KB: [half][col]
    __shared__ unsigned int cminS[COLS_PER_BLOCK]; // 2 KB

    // Stage the block's B-side slice (both halves) + init col-min array.
    #pragma unroll
    for (int p = 0; p < (2 * COLS_PER_BLOCK) / BLOCK; ++p) {
        int idx = p * BLOCK + tid;
        int h = idx >> 9;           // /COLS_PER_BLOCK
        int c = idx & (COLS_PER_BLOCK - 1);
        sBf[idx] = Bside[h * NPTS + colBase + c];
    }
    for (int c = tid; c < COLS_PER_BLOCK; c += BLOCK)
        cminS[c] = 0x7F800000u;
    __syncthreads();

    const uint4* __restrict__ Ah = Aside + half * NPTS;
    const uint4* sB = sBf + half * COLS_PER_BLOCK;   // this lane's k-half

    const f32x16 zacc = {0.f,0.f,0.f,0.f, 0.f,0.f,0.f,0.f,
                         0.f,0.f,0.f,0.f, 0.f,0.f,0.f,0.f};

    #pragma unroll 1
    for (int a = 0; a < ATILES; ++a) {
        uint4 ac = Ah[rowBase + a * 32 + ln31];
        bf16x8 af = __builtin_bit_cast(bf16x8, ac);

        #pragma unroll 2
        for (int s = 0; s < CSTEPS; ++s) {
            bf16x8 b0 = __builtin_bit_cast(bf16x8, sB[s * 64 + ln31]);
            bf16x8 b1 = __builtin_bit_cast(bf16x8, sB[s * 64 + 32 + ln31]);
            f32x16 acc0 = __builtin_amdgcn_mfma_f32_32x32x16_bf16(af, b0, zacc, 0, 0, 0);
            f32x16 acc1 = __builtin_amdgcn_mfma_f32_32x32x16_bf16(af, b1, zacc, 0, 0, 0);
            // Column mins: tree over 16 rows per lane, combine halves, merge.
            float c0 = fmaxf(tree16(acc0), 0.0f);
            float c1 = fmaxf(tree16(acc1), 0.0f);
            c0 = fminf(c0, __shfl_xor(c0, 32, 64));
            c1 = fminf(c1, __shfl_xor(c1, 32, 64));
            if (half == 0) {
                atomicMin(&cminS[s * 64 + ln31],      __float_as_uint(c0));
                atomicMin(&cminS[s * 64 + 32 + ln31], __float_as_uint(c1));
            }
        }
    }

    __syncthreads();
    for (int c = tid; c < COLS_PER_BLOCK; c += BLOCK)
        atomicMin(&outMin[colBase + c], cminS[c]);   // already clamped >= 0

    // ------------------- ticket: last block finalizes -----------------------
    // All cross-block data flows through device-scope atomics (coherent
    // point); only completion of this thread's atomics is required before
    // signaling (r8-verified).
    __shared__ unsigned int sTicket;
    asm volatile("s_waitcnt vmcnt(0)" ::: "memory");
    __syncthreads();
    if (tid == 0) sTicket = atomicAdd(ticket, 1u);
    __syncthreads();
    if (sTicket != (unsigned)(NBLOCKS - 1)) return;

    // Read via identity atomics (coherent across XCDs), weighted sums.
    float np = 0.f, dp = 0.f, ng = 0.f, dg = 0.f;
    for (int i = tid; i < NPTS; i += BLOCK) {
        float v = __uint_as_float(atomicMin(&minP[i], 0xFFFFFFFFu));
        float w = wpred[i];
        np = fmaf(w, v, np); dp += w;
        float u = __uint_as_float(atomicMin(&minG[i], 0xFFFFFFFFu));
        float x = wgt[i];
        ng = fmaf(x, u, ng); dg += x;
    }
    #pragma unroll
    for (int off = 1; off < 64; off <<= 1) {
        np += __shfl_xor(np, off, 64);
        dp += __shfl_xor(dp, off, 64);
        ng += __shfl_xor(ng, off, 64);
        dg += __shfl_xor(dg, off, 64);
    }
    __shared__ float sred[4][WAVES];
    if (lane == 0) { sred[0][wv] = np; sred[1][wv] = dp;
                     sred[2][wv] = ng; sred[3][wv] = dg; }
    __syncthreads();
    if (tid == 0) {
        float NP = 0.f, DP = 0.f, NG = 0.f, DG = 0.f;
        #pragma unroll
        for (int k = 0; k < WAVES; ++k) {
            NP += sred[0][k]; DP += sred[1][k];
            NG += sred[2][k]; DG += sred[3][k];
        }
        out[0] = NP / fmaxf(DP, 1e-9f) + NG / fmaxf(DG, 1e-9f);
    }
}

// ---------------------------------------------------------------------------
extern "C" void kernel_launch(void* const* d_in, const int* in_sizes, int n_in,
                              void* d_out, int out_size, void* d_ws, size_t ws_size,
                              hipStream_t stream)
{
    const float* pred  = (const float*)d_in[0];   // (P,3)
    const float* gt    = (const float*)d_in[1];   // (G,3)
    const float* wpred = (const float*)d_in[2];   // (P,)
    const float* wgt   = (const float*)d_in[3];   // (G,)
    float* out = (float*)d_out;

    // ws: Af|Bf|Ag|Bp (512K each) | minP(64K) | minG(64K) | ticket (~2.13 MB)
    uint4* Af = (uint4*)d_ws;
    uint4* Bf = Af + 2 * NPTS;
    uint4* Ag = Bf + 2 * NPTS;
    uint4* Bp = Ag + 2 * NPTS;
    unsigned int* minP = (unsigned int*)(Bp + 2 * NPTS);
    unsigned int* minG = minP + NPTS;
    unsigned int* ticket = minG + NPTS;

    pack_init_kernel<<<NPTS / 256, 256, 0, stream>>>(
        pred, gt, Af, Bf, Ag, Bp, minP, minG, ticket);

    chamfer_mfma_kernel<<<dim3(NBX, NBY, 2), BLOCK, 0, stream>>>(
        Af, Bf, Ag, Bp, minP, minG, wpred, wgt, ticket, out);
}

// Round 10
// 98.821 us; speedup vs baseline: 3.2685x; 1.0114x over previous
//
#include <hip/hip_runtime.h>
#include <math.h>

// ---------------------------------------------------------------------------
// Chamfer distance via MFMA (gfx950) — round 10: DS-pipe diet.
//
// d2(p,g) = p^2 + g^2 - 2 p.g computed entirely inside
// v_mfma_f32_32x32x16_bf16 via bf16 hi/lo (Dekker) split over K=16 slots
// (HW-verified absmax 0.0, rounds 1-9). r8 removed the fence tax; r9 made
// both directions lane-local via two swapped-operand passes (45 us).
//
// r9 floor analysis: DS pipe ~17 us (2 ds_read + 2 shfl + 2 LDS atomics per
// wave-step) > MFMA 6.8 us > VALU 6 us. This round cuts DS ops 3x:
//   - loop swap (s outer, a inner): B fragments ds_read ONCE per s, A
//     fragments hoisted out of the loop entirely;
//   - min accumulated across the 2 a-tiles in registers (tree32, min3-
//     shaped) -> one tree + one atomic per col-group per s;
//   - no cross-half shfl: both halves atomicMin the same cminS address
//     (2-way same-address atomic, cheap; r3-verified).
// Per s: 2 ds_read + 4 MFMA + 2 tree32 + 2 atomics (was 4/4/4 tree16/4 shfl/
// 4 atomics per 2 a-steps). Only 2 accs live at a time (col-group serial).
// Tripwires: VGPR <= 64, WRITE <= 8 MB, FETCH <= 6 MB.
// ---------------------------------------------------------------------------

constexpr int NPTS  = 16384;
constexpr int BLOCK = 512;                        // 8 waves
constexpr int WAVES = BLOCK / 64;

constexpr int ROWS_PER_BLOCK = 512;
constexpr int COLS_PER_BLOCK = 512;
constexpr int NBX = NPTS / ROWS_PER_BLOCK;        // 32
constexpr int NBY = NPTS / COLS_PER_BLOCK;        // 32
constexpr int NBLOCKS = NBX * NBY * 2;            // 2048 (both passes)
constexpr int ROWS_PER_WAVE = ROWS_PER_BLOCK / WAVES;   // 64 (2 x 32-row tiles)
constexpr int CSTEPS = COLS_PER_BLOCK / 64;       // 8 (two 32-col groups/step)

typedef __attribute__((ext_vector_type(8)))  __bf16 bf16x8;
typedef __attribute__((ext_vector_type(16))) float  f32x16;

__device__ inline unsigned short f2bf(float f) {          // RNE float->bf16
    unsigned u = __float_as_uint(f);
    u += 0x7FFFu + ((u >> 16) & 1u);
    return (unsigned short)(u >> 16);
}
__device__ inline float bf2f(unsigned short h) {
    return __uint_as_float(((unsigned)h) << 16);
}
__device__ inline unsigned pk(unsigned short lo, unsigned short hi) {
    return (unsigned)lo | ((unsigned)hi << 16);
}

// ---------------------------------------------------------------------------
// Fragment layouts (HW-verified pairing, rounds 1-9). For vector v with norm
// s (split hi/lo), slot sum of A(v,s) . B(w,t) = v.w + s + t:
//   A half0: [vhx,vhy,vhz, vlx,vly,vlz, vhx,vhy]
//   A half1: [vhz, s_h, s_l, 1, 1, vlx, vly, vlz]
//   B half0: [whx,why,whz, whx,why,whz, wlx,wly]
//   B half1: [wlz, 1, 1, t_h, t_l, wlx, wly, wlz]
// Pass 1: A(p,p2) . B(-2g,g2) = d2.  Pass 2: A(-2g,g2) . B(p,p2) = d2.
// Arrays (half-major, X[half*NPTS+i]):
//   Af = A-layout(p,p2)    Bf = B-layout(-2g,g2)
//   Ag = A-layout(-2g,g2)  Bp = B-layout(p,p2)
// ---------------------------------------------------------------------------
__global__ __launch_bounds__(256) void pack_init_kernel(
    const float* __restrict__ pred, const float* __restrict__ gt,
    uint4* __restrict__ Af, uint4* __restrict__ Bf,
    uint4* __restrict__ Ag, uint4* __restrict__ Bp,
    unsigned int* __restrict__ minP, unsigned int* __restrict__ minG,
    unsigned int* __restrict__ ticket)
{
    const unsigned short ONE = 0x3F80;
    int i = blockIdx.x * 256 + threadIdx.x;
    if (i == 0) *ticket = 0u;
    if (i >= NPTS) return;

    {   // pred: split p, p2
        float x = pred[3*i], y = pred[3*i+1], z = pred[3*i+2];
        unsigned short hx = f2bf(x), hy = f2bf(y), hz = f2bf(z);
        unsigned short lx = f2bf(x - bf2f(hx));
        unsigned short ly = f2bf(y - bf2f(hy));
        unsigned short lz = f2bf(z - bf2f(hz));
        float p2 = fmaf(x, x, fmaf(y, y, z * z));
        unsigned short sh = f2bf(p2), sl = f2bf(p2 - bf2f(sh));
        uint4 a0, a1, b0, b1;
        a0.x = pk(hx, hy); a0.y = pk(hz, lx); a0.z = pk(ly, lz); a0.w = pk(hx, hy);
        a1.x = pk(hz, sh); a1.y = pk(sl, ONE); a1.z = pk(ONE, lx); a1.w = pk(ly, lz);
        b0.x = pk(hx, hy); b0.y = pk(hz, hx); b0.z = pk(hy, hz); b0.w = pk(lx, ly);
        b1.x = pk(lz, ONE); b1.y = pk(ONE, sh); b1.z = pk(sl, lx); b1.w = pk(ly, lz);
        Af[i] = a0; Af[NPTS + i] = a1;
        Bp[i] = b0; Bp[NPTS + i] = b1;
    }
    {   // gt: split m = -2g, g2
        float gx = gt[3*i], gy = gt[3*i+1], gz = gt[3*i+2];
        float mx = -2.0f * gx, my = -2.0f * gy, mz = -2.0f * gz;
        unsigned short hx = f2bf(mx), hy = f2bf(my), hz = f2bf(mz);
        unsigned short lx = f2bf(mx - bf2f(hx));
        unsigned short ly = f2bf(my - bf2f(hy));
        unsigned short lz = f2bf(mz - bf2f(hz));
        float g2 = fmaf(gx, gx, fmaf(gy, gy, gz * gz));
        unsigned short sh = f2bf(g2), sl = f2bf(g2 - bf2f(sh));
        uint4 a0, a1, b0, b1;
        a0.x = pk(hx, hy); a0.y = pk(hz, lx); a0.z = pk(ly, lz); a0.w = pk(hx, hy);
        a1.x = pk(hz, sh); a1.y = pk(sl, ONE); a1.z = pk(ONE, lx); a1.w = pk(ly, lz);
        b0.x = pk(hx, hy); b0.y = pk(hz, hx); b0.z = pk(hy, hz); b0.w = pk(lx, ly);
        b1.x = pk(lz, ONE); b1.y = pk(ONE, sh); b1.z = pk(sl, lx); b1.w = pk(ly, lz);
        Ag[i] = a0; Ag[NPTS + i] = a1;
        Bf[i] = b0; Bf[NPTS + i] = b1;
    }
    minP[i] = 0x7F800000u;   // +inf
    minG[i] = 0x7F800000u;
}

// Min of 32 values (two accumulators), min3-shaped for v_min3 fusion.
__device__ inline float tree32(const f32x16 a, const f32x16 b) {
    float m0 = fminf(fminf(a[0],  a[1]),  a[2]);
    float m1 = fminf(fminf(a[3],  a[4]),  a[5]);
    float m2 = fminf(fminf(a[6],  a[7]),  a[8]);
    float m3 = fminf(fminf(a[9],  a[10]), a[11]);
    float m4 = fminf(fminf(a[12], a[13]), a[14]);
    float m5 = fminf(fminf(a[15], b[0]),  b[1]);
    float m6 = fminf(fminf(b[2],  b[3]),  b[4]);
    float m7 = fminf(fminf(b[5],  b[6]),  b[7]);
    float m8 = fminf(fminf(b[8],  b[9]),  b[10]);
    float m9 = fminf(fminf(b[11], b[12]), b[13]);
    float ma = fminf(b[14], b[15]);
    float n0 = fminf(fminf(m0, m1), m2);
    float n1 = fminf(fminf(m3, m4), m5);
    float n2 = fminf(fminf(m6, m7), m8);
    float n3 = fminf(fminf(m9, ma), n0);
    return fminf(fminf(n1, n2), n3);
}

// ---------------------------------------------------------------------------
// Main kernel: grid (32,32,2); block tile 512 A-rows x 512 B-cols, 8 waves.
// z picks the pass (which cloud is on the lane axis). Wave w owns A-rows
// [w*64, w*64+64) as two 32-row fragments, hoisted out of the s-loop.
// C/D layout (HW-verified): col = lane&31, row = (reg&3)+8*(reg>>2)+4*(lane>>5)
// -> per-lane tree32 over both a-tiles = min over this wave's 64 A-rows for
// this lane's B-col; halves/waves merge in cminS via 64-lane LDS atomicMin
// (two halves share an address: 2-way same-address atomic, cheap); blocks
// merge via global atomicMin. No __threadfence (r8-verified protocol).
// ---------------------------------------------------------------------------
__global__ __launch_bounds__(BLOCK, 2) void chamfer_mfma_kernel(
    const uint4* __restrict__ Af, const uint4* __restrict__ Bf,
    const uint4* __restrict__ Ag, const uint4* __restrict__ Bp,
    unsigned int* __restrict__ minP, unsigned int* __restrict__ minG,
    const float* __restrict__ wpred, const float* __restrict__ wgt,
    unsigned int* __restrict__ ticket, float* __restrict__ out)
{
    const int tid  = threadIdx.x;
    const int wv   = tid >> 6;
    const int lane = tid & 63;
    const int half = lane >> 5;
    const int ln31 = lane & 31;

    const uint4* __restrict__ Aside;
    const uint4* __restrict__ Bside;
    unsigned int* __restrict__ outMin;
    if (blockIdx.z == 0) { Aside = Af; Bside = Bf; outMin = minG; }
    else                 { Aside = Ag; Bside = Bp; outMin = minP; }

    const int rowBase = blockIdx.x * ROWS_PER_BLOCK + wv * ROWS_PER_WAVE;
    const int colBase = blockIdx.y * COLS_PER_BLOCK;

    __shared__ uint4 sBf[2 * COLS_PER_BLOCK];      // 16 KB: [half][col]
    __shared__ unsigned int cminS[COLS_PER_BLOCK]; // 2 KB

    // Stage the block's B-side slice (both halves) + init col-min array.
    #pragma unroll
    for (int p = 0; p < (2 * COLS_PER_BLOCK) / BLOCK; ++p) {
        int idx = p * BLOCK + tid;
        int h = idx >> 9;           // /COLS_PER_BLOCK
        int c = idx & (COLS_PER_BLOCK - 1);
        sBf[idx] = Bside[h * NPTS + colBase + c];
    }
    for (int c = tid; c < COLS_PER_BLOCK; c += BLOCK)
        cminS[c] = 0x7F800000u;
    __syncthreads();

    const uint4* __restrict__ Ah = Aside + half * NPTS;
    const uint4* sB = sBf + half * COLS_PER_BLOCK;   // this lane's k-half

    // A fragments: both 32-row tiles, loaded once.
    bf16x8 af0 = __builtin_bit_cast(bf16x8, Ah[rowBase + ln31]);
    bf16x8 af1 = __builtin_bit_cast(bf16x8, Ah[rowBase + 32 + ln31]);

    const f32x16 zacc = {0.f,0.f,0.f,0.f, 0.f,0.f,0.f,0.f,
                         0.f,0.f,0.f,0.f, 0.f,0.f,0.f,0.f};

    #pragma unroll 2
    for (int s = 0; s < CSTEPS; ++s) {
        bf16x8 b0 = __builtin_bit_cast(bf16x8, sB[s * 64 + ln31]);
        bf16x8 b1 = __builtin_bit_cast(bf16x8, sB[s * 64 + 32 + ln31]);
        // Col-group 0: both a-tiles, reduce, merge.
        {
            f32x16 p = __builtin_amdgcn_mfma_f32_32x32x16_bf16(af0, b0, zacc, 0, 0, 0);
            f32x16 q = __builtin_amdgcn_mfma_f32_32x32x16_bf16(af1, b0, zacc, 0, 0, 0);
            float c0 = fmaxf(tree32(p, q), 0.0f);
            atomicMin(&cminS[s * 64 + ln31], __float_as_uint(c0));
        }
        // Col-group 1.
        {
            f32x16 p = __builtin_amdgcn_mfma_f32_32x32x16_bf16(af0, b1, zacc, 0, 0, 0);
            f32x16 q = __builtin_amdgcn_mfma_f32_32x32x16_bf16(af1, b1, zacc, 0, 0, 0);
            float c1 = fmaxf(tree32(p, q), 0.0f);
            atomicMin(&cminS[s * 64 + 32 + ln31], __float_as_uint(c1));
        }
    }

    __syncthreads();
    for (int c = tid; c < COLS_PER_BLOCK; c += BLOCK)
        atomicMin(&outMin[colBase + c], cminS[c]);   // already clamped >= 0

    // ------------------- ticket: last block finalizes -----------------------
    // All cross-block data flows through device-scope atomics (coherent
    // point); only completion of this thread's atomics is required before
    // signaling (r8-verified).
    __shared__ unsigned int sTicket;
    asm volatile("s_waitcnt vmcnt(0)" ::: "memory");
    __syncthreads();
    if (tid == 0) sTicket = atomicAdd(ticket, 1u);
    __syncthreads();
    if (sTicket != (unsigned)(NBLOCKS - 1)) return;

    // Read via identity atomics (coherent across XCDs), weighted sums.
    float np = 0.f, dp = 0.f, ng = 0.f, dg = 0.f;
    for (int i = tid; i < NPTS; i += BLOCK) {
        float v = __uint_as_float(atomicMin(&minP[i], 0xFFFFFFFFu));
        float w = wpred[i];
        np = fmaf(w, v, np); dp += w;
        float u = __uint_as_float(atomicMin(&minG[i], 0xFFFFFFFFu));
        float x = wgt[i];
        ng = fmaf(x, u, ng); dg += x;
    }
    #pragma unroll
    for (int off = 1; off < 64; off <<= 1) {
        np += __shfl_xor(np, off, 64);
        dp += __shfl_xor(dp, off, 64);
        ng += __shfl_xor(ng, off, 64);
        dg += __shfl_xor(dg, off, 64);
    }
    __shared__ float sred[4][WAVES];
    if (lane == 0) { sred[0][wv] = np; sred[1][wv] = dp;
                     sred[2][wv] = ng; sred[3][wv] = dg; }
    __syncthreads();
    if (tid == 0) {
        float NP = 0.f, DP = 0.f, NG = 0.f, DG = 0.f;
        #pragma unroll
        for (int k = 0; k < WAVES; ++k) {
            NP += sred[0][k]; DP += sred[1][k];
            NG += sred[2][k]; DG += sred[3][k];
        }
        out[0] = NP / fmaxf(DP, 1e-9f) + NG / fmaxf(DG, 1e-9f);
    }
}

// ---------------------------------------------------------------------------
extern "C" void kernel_launch(void* const* d_in, const int* in_sizes, int n_in,
                              void* d_out, int out_size, void* d_ws, size_t ws_size,
                              hipStream_t stream)
{
    const float* pred  = (const float*)d_in[0];   // (P,3)
    const float* gt    = (const float*)d_in[1];   // (G,3)
    const float* wpred = (const float*)d_in[2];   // (P,)
    const float* wgt   = (const float*)d_in[3];   // (G,)
    float* out = (float*)d_out;

    // ws: Af|Bf|Ag|Bp (512K each) | minP(64K) | minG(64K) | ticket (~2.13 MB)
    uint4* Af = (uint4*)d_ws;
    uint4* Bf = Af + 2 * NPTS;
    uint4* Ag = Bf + 2 * NPTS;
    uint4* Bp = Ag + 2 * NPTS;
    unsigned int* minP = (unsigned int*)(Bp + 2 * NPTS);
    unsigned int* minG = minP + NPTS;
    unsigned int* ticket = minG + NPTS;

    pack_init_kernel<<<NPTS / 256, 256, 0, stream>>>(
        pred, gt, Af, Bf, Ag, Bp, minP, minG, ticket);

    chamfer_mfma_kernel<<<dim3(NBX, NBY, 2), BLOCK, 0, stream>>>(
        Af, Bf, Ag, Bp, minP, minG, wpred, wgt, ticket, out);
}

// Round 11
// 98.814 us; speedup vs baseline: 3.2687x; 1.0001x over previous
//
#include <hip/hip_runtime.h>
#include <math.h>

// ---------------------------------------------------------------------------
// Chamfer distance via MFMA (gfx950) — round 11: break acc-reuse serialization.
//
// d2(p,g) = p^2 + g^2 - 2 p.g computed entirely inside
// v_mfma_f32_32x32x16_bf16 via bf16 hi/lo (Dekker) split over K=16 slots
// (HW-verified absmax 0.0, rounds 1-10).
//
// r10 post-mortem: cutting DS+VALU issue 35% left wall unchanged (45->44us)
// -> not throughput-bound on any pipe. Occupancy ~30% (~1.2 blocks/CU),
// VALUBusy 20% -> waves >90% stalled on the per-group serial chain
// ds_read -> MFMA -> MFMA -> tree32 -> atomic. With VGPR_Count=36 the
// allocator gave minimal accumulator sets, so successive groups serialize on
// acc register reuse (group k+1's MFMA waits for group k's tree to read).
// This round: issue all 4 MFMAs of an s-step into 4 DISTINCT accumulators,
// then do the two tree32s -> up to 8 independent chains under unroll 2.
// Everything else byte-identical to r10 (staging, reductions, ticket, grid).
// Tripwires: WRITE <= 8 MB, FETCH <= 6 MB (deterministic tens-of-MB = spill).
// ---------------------------------------------------------------------------

constexpr int NPTS  = 16384;
constexpr int BLOCK = 512;                        // 8 waves
constexpr int WAVES = BLOCK / 64;

constexpr int ROWS_PER_BLOCK = 512;
constexpr int COLS_PER_BLOCK = 512;
constexpr int NBX = NPTS / ROWS_PER_BLOCK;        // 32
constexpr int NBY = NPTS / COLS_PER_BLOCK;        // 32
constexpr int NBLOCKS = NBX * NBY * 2;            // 2048 (both passes)
constexpr int ROWS_PER_WAVE = ROWS_PER_BLOCK / WAVES;   // 64 (2 x 32-row tiles)
constexpr int CSTEPS = COLS_PER_BLOCK / 64;       // 8 (two 32-col groups/step)

typedef __attribute__((ext_vector_type(8)))  __bf16 bf16x8;
typedef __attribute__((ext_vector_type(16))) float  f32x16;

__device__ inline unsigned short f2bf(float f) {          // RNE float->bf16
    unsigned u = __float_as_uint(f);
    u += 0x7FFFu + ((u >> 16) & 1u);
    return (unsigned short)(u >> 16);
}
__device__ inline float bf2f(unsigned short h) {
    return __uint_as_float(((unsigned)h) << 16);
}
__device__ inline unsigned pk(unsigned short lo, unsigned short hi) {
    return (unsigned)lo | ((unsigned)hi << 16);
}

// ---------------------------------------------------------------------------
// Fragment layouts (HW-verified pairing, rounds 1-10). For vector v with norm
// s (split hi/lo), slot sum of A(v,s) . B(w,t) = v.w + s + t:
//   A half0: [vhx,vhy,vhz, vlx,vly,vlz, vhx,vhy]
//   A half1: [vhz, s_h, s_l, 1, 1, vlx, vly, vlz]
//   B half0: [whx,why,whz, whx,why,whz, wlx,wly]
//   B half1: [wlz, 1, 1, t_h, t_l, wlx, wly, wlz]
// Pass 1: A(p,p2) . B(-2g,g2) = d2.  Pass 2: A(-2g,g2) . B(p,p2) = d2.
// Arrays (half-major, X[half*NPTS+i]):
//   Af = A-layout(p,p2)    Bf = B-layout(-2g,g2)
//   Ag = A-layout(-2g,g2)  Bp = B-layout(p,p2)
// ---------------------------------------------------------------------------
__global__ __launch_bounds__(256) void pack_init_kernel(
    const float* __restrict__ pred, const float* __restrict__ gt,
    uint4* __restrict__ Af, uint4* __restrict__ Bf,
    uint4* __restrict__ Ag, uint4* __restrict__ Bp,
    unsigned int* __restrict__ minP, unsigned int* __restrict__ minG,
    unsigned int* __restrict__ ticket)
{
    const unsigned short ONE = 0x3F80;
    int i = blockIdx.x * 256 + threadIdx.x;
    if (i == 0) *ticket = 0u;
    if (i >= NPTS) return;

    {   // pred: split p, p2
        float x = pred[3*i], y = pred[3*i+1], z = pred[3*i+2];
        unsigned short hx = f2bf(x), hy = f2bf(y), hz = f2bf(z);
        unsigned short lx = f2bf(x - bf2f(hx));
        unsigned short ly = f2bf(y - bf2f(hy));
        unsigned short lz = f2bf(z - bf2f(hz));
        float p2 = fmaf(x, x, fmaf(y, y, z * z));
        unsigned short sh = f2bf(p2), sl = f2bf(p2 - bf2f(sh));
        uint4 a0, a1, b0, b1;
        a0.x = pk(hx, hy); a0.y = pk(hz, lx); a0.z = pk(ly, lz); a0.w = pk(hx, hy);
        a1.x = pk(hz, sh); a1.y = pk(sl, ONE); a1.z = pk(ONE, lx); a1.w = pk(ly, lz);
        b0.x = pk(hx, hy); b0.y = pk(hz, hx); b0.z = pk(hy, hz); b0.w = pk(lx, ly);
        b1.x = pk(lz, ONE); b1.y = pk(ONE, sh); b1.z = pk(sl, lx); b1.w = pk(ly, lz);
        Af[i] = a0; Af[NPTS + i] = a1;
        Bp[i] = b0; Bp[NPTS + i] = b1;
    }
    {   // gt: split m = -2g, g2
        float gx = gt[3*i], gy = gt[3*i+1], gz = gt[3*i+2];
        float mx = -2.0f * gx, my = -2.0f * gy, mz = -2.0f * gz;
        unsigned short hx = f2bf(mx), hy = f2bf(my), hz = f2bf(mz);
        unsigned short lx = f2bf(mx - bf2f(hx));
        unsigned short ly = f2bf(my - bf2f(hy));
        unsigned short lz = f2bf(mz - bf2f(hz));
        float g2 = fmaf(gx, gx, fmaf(gy, gy, gz * gz));
        unsigned short sh = f2bf(g2), sl = f2bf(g2 - bf2f(sh));
        uint4 a0, a1, b0, b1;
        a0.x = pk(hx, hy); a0.y = pk(hz, lx); a0.z = pk(ly, lz); a0.w = pk(hx, hy);
        a1.x = pk(hz, sh); a1.y = pk(sl, ONE); a1.z = pk(ONE, lx); a1.w = pk(ly, lz);
        b0.x = pk(hx, hy); b0.y = pk(hz, hx); b0.z = pk(hy, hz); b0.w = pk(lx, ly);
        b1.x = pk(lz, ONE); b1.y = pk(ONE, sh); b1.z = pk(sl, lx); b1.w = pk(ly, lz);
        Ag[i] = a0; Ag[NPTS + i] = a1;
        Bf[i] = b0; Bf[NPTS + i] = b1;
    }
    minP[i] = 0x7F800000u;   // +inf
    minG[i] = 0x7F800000u;
}

// Min of 32 values (two accumulators), min3-shaped for v_min3 fusion.
__device__ inline float tree32(const f32x16 a, const f32x16 b) {
    float m0 = fminf(fminf(a[0],  a[1]),  a[2]);
    float m1 = fminf(fminf(a[3],  a[4]),  a[5]);
    float m2 = fminf(fminf(a[6],  a[7]),  a[8]);
    float m3 = fminf(fminf(a[9],  a[10]), a[11]);
    float m4 = fminf(fminf(a[12], a[13]), a[14]);
    float m5 = fminf(fminf(a[15], b[0]),  b[1]);
    float m6 = fminf(fminf(b[2],  b[3]),  b[4]);
    float m7 = fminf(fminf(b[5],  b[6]),  b[7]);
    float m8 = fminf(fminf(b[8],  b[9]),  b[10]);
    float m9 = fminf(fminf(b[11], b[12]), b[13]);
    float ma = fminf(b[14], b[15]);
    float n0 = fminf(fminf(m0, m1), m2);
    float n1 = fminf(fminf(m3, m4), m5);
    float n2 = fminf(fminf(m6, m7), m8);
    float n3 = fminf(fminf(m9, ma), n0);
    return fminf(fminf(n1, n2), n3);
}

// ---------------------------------------------------------------------------
// Main kernel: grid (32,32,2); block tile 512 A-rows x 512 B-cols, 8 waves.
// z picks the pass (which cloud is on the lane axis). Wave w owns A-rows
// [w*64, w*64+64) as two 32-row fragments, hoisted out of the s-loop.
// C/D layout (HW-verified): col = lane&31, row = (reg&3)+8*(reg>>2)+4*(lane>>5)
// -> per-lane tree32 over both a-tiles = min over this wave's 64 A-rows for
// this lane's B-col; halves/waves merge in cminS via 64-lane LDS atomicMin;
// blocks merge via global atomicMin. No __threadfence (r8-verified protocol).
// Per s-step: 4 MFMAs issued into 4 DISTINCT accs, then 2 tree32s (ILP).
// ---------------------------------------------------------------------------
__global__ __launch_bounds__(BLOCK, 2) void chamfer_mfma_kernel(
    const uint4* __restrict__ Af, const uint4* __restrict__ Bf,
    const uint4* __restrict__ Ag, const uint4* __restrict__ Bp,
    unsigned int* __restrict__ minP, unsigned int* __restrict__ minG,
    const float* __restrict__ wpred, const float* __restrict__ wgt,
    unsigned int* __restrict__ ticket, float* __restrict__ out)
{
    const int tid  = threadIdx.x;
    const int wv   = tid >> 6;
    const int lane = tid & 63;
    const int half = lane >> 5;
    const int ln31 = lane & 31;

    const uint4* __restrict__ Aside;
    const uint4* __restrict__ Bside;
    unsigned int* __restrict__ outMin;
    if (blockIdx.z == 0) { Aside = Af; Bside = Bf; outMin = minG; }
    else                 { Aside = Ag; Bside = Bp; outMin = minP; }

    const int rowBase = blockIdx.x * ROWS_PER_BLOCK + wv * ROWS_PER_WAVE;
    const int colBase = blockIdx.y * COLS_PER_BLOCK;

    __shared__ uint4 sBf[2 * COLS_PER_BLOCK];      // 16 KB: [half][col]
    __shared__ unsigned int cminS[COLS_PER_BLOCK]; // 2 KB

    // Stage the block's B-side slice (both halves) + init col-min array.
    #pragma unroll
    for (int p = 0; p < (2 * COLS_PER_BLOCK) / BLOCK; ++p) {
        int idx = p * BLOCK + tid;
        int h = idx >> 9;           // /COLS_PER_BLOCK
        int c = idx & (COLS_PER_BLOCK - 1);
        sBf[idx] = Bside[h * NPTS + colBase + c];
    }
    for (int c = tid; c < COLS_PER_BLOCK; c += BLOCK)
        cminS[c] = 0x7F800000u;
    __syncthreads();

    const uint4* __restrict__ Ah = Aside + half * NPTS;
    const uint4* sB = sBf + half * COLS_PER_BLOCK;   // this lane's k-half

    // A fragments: both 32-row tiles, loaded once.
    bf16x8 af0 = __builtin_bit_cast(bf16x8, Ah[rowBase + ln31]);
    bf16x8 af1 = __builtin_bit_cast(bf16x8, Ah[rowBase + 32 + ln31]);

    const f32x16 zacc = {0.f,0.f,0.f,0.f, 0.f,0.f,0.f,0.f,
                         0.f,0.f,0.f,0.f, 0.f,0.f,0.f,0.f};

    #pragma unroll 2
    for (int s = 0; s < CSTEPS; ++s) {
        bf16x8 b0 = __builtin_bit_cast(bf16x8, sB[s * 64 + ln31]);
        bf16x8 b1 = __builtin_bit_cast(bf16x8, sB[s * 64 + 32 + ln31]);
        // All 4 MFMAs first (4 distinct accumulators -> independent chains).
        f32x16 p0 = __builtin_amdgcn_mfma_f32_32x32x16_bf16(af0, b0, zacc, 0, 0, 0);
        f32x16 q0 = __builtin_amdgcn_mfma_f32_32x32x16_bf16(af1, b0, zacc, 0, 0, 0);
        f32x16 p1 = __builtin_amdgcn_mfma_f32_32x32x16_bf16(af0, b1, zacc, 0, 0, 0);
        f32x16 q1 = __builtin_amdgcn_mfma_f32_32x32x16_bf16(af1, b1, zacc, 0, 0, 0);
        // Then the two reductions + merges.
        float c0 = fmaxf(tree32(p0, q0), 0.0f);
        float c1 = fmaxf(tree32(p1, q1), 0.0f);
        atomicMin(&cminS[s * 64 + ln31],      __float_as_uint(c0));
        atomicMin(&cminS[s * 64 + 32 + ln31], __float_as_uint(c1));
    }

    __syncthreads();
    for (int c = tid; c < COLS_PER_BLOCK; c += BLOCK)
        atomicMin(&outMin[colBase + c], cminS[c]);   // already clamped >= 0

    // ------------------- ticket: last block finalizes -----------------------
    // All cross-block data flows through device-scope atomics (coherent
    // point); only completion of this thread's atomics is required before
    // signaling (r8-verified).
    __shared__ unsigned int sTicket;
    asm volatile("s_waitcnt vmcnt(0)" ::: "memory");
    __syncthreads();
    if (tid == 0) sTicket = atomicAdd(ticket, 1u);
    __syncthreads();
    if (sTicket != (unsigned)(NBLOCKS - 1)) return;

    // Read via identity atomics (coherent across XCDs), weighted sums.
    float np = 0.f, dp = 0.f, ng = 0.f, dg = 0.f;
    for (int i = tid; i < NPTS; i += BLOCK) {
        float v = __uint_as_float(atomicMin(&minP[i], 0xFFFFFFFFu));
        float w = wpred[i];
        np = fmaf(w, v, np); dp += w;
        float u = __uint_as_float(atomicMin(&minG[i], 0xFFFFFFFFu));
        float x = wgt[i];
        ng = fmaf(x, u, ng); dg += x;
    }
    #pragma unroll
    for (int off = 1; off < 64; off <<= 1) {
        np += __shfl_xor(np, off, 64);
        dp += __shfl_xor(dp, off, 64);
        ng += __shfl_xor(ng, off, 64);
        dg += __shfl_xor(dg, off, 64);
    }
    __shared__ float sred[4][WAVES];
    if (lane == 0) { sred[0][wv] = np; sred[1][wv] = dp;
                     sred[2][wv] = ng; sred[3][wv] = dg; }
    __syncthreads();
    if (tid == 0) {
        float NP = 0.f, DP = 0.f, NG = 0.f, DG = 0.f;
        #pragma unroll
        for (int k = 0; k < WAVES; ++k) {
            NP += sred[0][k]; DP += sred[1][k];
            NG += sred[2][k]; DG += sred[3][k];
        }
        out[0] = NP / fmaxf(DP, 1e-9f) + NG / fmaxf(DG, 1e-9f);
    }
}

// ---------------------------------------------------------------------------
extern "C" void kernel_launch(void* const* d_in, const int* in_sizes, int n_in,
                              void* d_out, int out_size, void* d_ws, size_t ws_size,
                              hipStream_t stream)
{
    const float* pred  = (const float*)d_in[0];   // (P,3)
    const float* gt    = (const float*)d_in[1];   // (G,3)
    const float* wpred = (const float*)d_in[2];   // (P,)
    const float* wgt   = (const float*)d_in[3];   // (G,)
    float* out = (float*)d_out;

    // ws: Af|Bf|Ag|Bp (512K each) | minP(64K) | minG(64K) | ticket (~2.13 MB)
    uint4* Af = (uint4*)d_ws;
    uint4* Bf = Af + 2 * NPTS;
    uint4* Ag = Bf + 2 * NPTS;
    uint4* Bp = Ag + 2 * NPTS;
    unsigned int* minP = (unsigned int*)(Bp + 2 * NPTS);
    unsigned int* minG = minP + NPTS;
    unsigned int* ticket = minG + NPTS;

    pack_init_kernel<<<NPTS / 256, 256, 0, stream>>>(
        pred, gt, Af, Bf, Ag, Bp, minP, minG, ticket);

    chamfer_mfma_kernel<<<dim3(NBX, NBY, 2), BLOCK, 0, stream>>>(
        Af, Bf, Ag, Bp, minP, minG, wpred, wgt, ticket, out);
}

// Round 12
// 83.416 us; speedup vs baseline: 3.8720x; 1.1846x over previous
//
#include <hip/hip_runtime.h>
#include <math.h>

// ---------------------------------------------------------------------------
// Chamfer distance via MFMA (gfx950) — round 12: kill the per-block epilogue.
//
// d2(p,g) = p^2 + g^2 - 2 p.g computed entirely inside
// v_mfma_f32_32x32x16_bf16 via bf16 hi/lo (Dekker) split over K=16 slots
// (HW-verified absmax 0.0, rounds 1-11).
//
// r9-r11: +/-35% inner-loop issue changes moved wall 0% -> block lifetime is
// dominated by per-block FIXED cost: global-atomic drain (vmcnt(0)) + ticket
// atomicAdd on one hot line (2048 contenders) + last-block serial finalize on
// the critical path. This round:
//   1. Ticket protocol REMOVED -> separate finalize dispatch (1 block). Main
//      blocks end right after issuing their atomicMins (end-of-dispatch
//      release guarantees visibility to the next kernel; plain loads there).
//   2. Blocks halved: COLS_PER_BLOCK 512->1024, grid (32,16,2)=1024 blocks,
//      4/CU exactly resident (LDS 36.9 KB). Staging amortized 2x. Inner loop
//      byte-identical (CSTEPS 8->16).
// Tripwires: VGPR ~36, WRITE <= 8 MB, FETCH <= 10 MB.
// ---------------------------------------------------------------------------

constexpr int NPTS  = 16384;
constexpr int BLOCK = 512;                        // 8 waves
constexpr int WAVES = BLOCK / 64;

constexpr int ROWS_PER_BLOCK = 512;
constexpr int COLS_PER_BLOCK = 1024;
constexpr int NBX = NPTS / ROWS_PER_BLOCK;        // 32
constexpr int NBY = NPTS / COLS_PER_BLOCK;        // 16
constexpr int ROWS_PER_WAVE = ROWS_PER_BLOCK / WAVES;   // 64 (2 x 32-row tiles)
constexpr int CSTEPS = COLS_PER_BLOCK / 64;       // 16 (two 32-col groups/step)

typedef __attribute__((ext_vector_type(8)))  __bf16 bf16x8;
typedef __attribute__((ext_vector_type(16))) float  f32x16;

__device__ inline unsigned short f2bf(float f) {          // RNE float->bf16
    unsigned u = __float_as_uint(f);
    u += 0x7FFFu + ((u >> 16) & 1u);
    return (unsigned short)(u >> 16);
}
__device__ inline float bf2f(unsigned short h) {
    return __uint_as_float(((unsigned)h) << 16);
}
__device__ inline unsigned pk(unsigned short lo, unsigned short hi) {
    return (unsigned)lo | ((unsigned)hi << 16);
}

// ---------------------------------------------------------------------------
// Fragment layouts (HW-verified pairing, rounds 1-11). For vector v with norm
// s (split hi/lo), slot sum of A(v,s) . B(w,t) = v.w + s + t:
//   A half0: [vhx,vhy,vhz, vlx,vly,vlz, vhx,vhy]
//   A half1: [vhz, s_h, s_l, 1, 1, vlx, vly, vlz]
//   B half0: [whx,why,whz, whx,why,whz, wlx,wly]
//   B half1: [wlz, 1, 1, t_h, t_l, wlx, wly, wlz]
// Pass 1: A(p,p2) . B(-2g,g2) = d2.  Pass 2: A(-2g,g2) . B(p,p2) = d2.
// Arrays (half-major, X[half*NPTS+i]):
//   Af = A-layout(p,p2)    Bf = B-layout(-2g,g2)
//   Ag = A-layout(-2g,g2)  Bp = B-layout(p,p2)
// ---------------------------------------------------------------------------
__global__ __launch_bounds__(256) void pack_init_kernel(
    const float* __restrict__ pred, const float* __restrict__ gt,
    uint4* __restrict__ Af, uint4* __restrict__ Bf,
    uint4* __restrict__ Ag, uint4* __restrict__ Bp,
    unsigned int* __restrict__ minP, unsigned int* __restrict__ minG)
{
    const unsigned short ONE = 0x3F80;
    int i = blockIdx.x * 256 + threadIdx.x;
    if (i >= NPTS) return;

    {   // pred: split p, p2
        float x = pred[3*i], y = pred[3*i+1], z = pred[3*i+2];
        unsigned short hx = f2bf(x), hy = f2bf(y), hz = f2bf(z);
        unsigned short lx = f2bf(x - bf2f(hx));
        unsigned short ly = f2bf(y - bf2f(hy));
        unsigned short lz = f2bf(z - bf2f(hz));
        float p2 = fmaf(x, x, fmaf(y, y, z * z));
        unsigned short sh = f2bf(p2), sl = f2bf(p2 - bf2f(sh));
        uint4 a0, a1, b0, b1;
        a0.x = pk(hx, hy); a0.y = pk(hz, lx); a0.z = pk(ly, lz); a0.w = pk(hx, hy);
        a1.x = pk(hz, sh); a1.y = pk(sl, ONE); a1.z = pk(ONE, lx); a1.w = pk(ly, lz);
        b0.x = pk(hx, hy); b0.y = pk(hz, hx); b0.z = pk(hy, hz); b0.w = pk(lx, ly);
        b1.x = pk(lz, ONE); b1.y = pk(ONE, sh); b1.z = pk(sl, lx); b1.w = pk(ly, lz);
        Af[i] = a0; Af[NPTS + i] = a1;
        Bp[i] = b0; Bp[NPTS + i] = b1;
    }
    {   // gt: split m = -2g, g2
        float gx = gt[3*i], gy = gt[3*i+1], gz = gt[3*i+2];
        float mx = -2.0f * gx, my = -2.0f * gy, mz = -2.0f * gz;
        unsigned short hx = f2bf(mx), hy = f2bf(my), hz = f2bf(mz);
        unsigned short lx = f2bf(mx - bf2f(hx));
        unsigned short ly = f2bf(my - bf2f(hy));
        unsigned short lz = f2bf(mz - bf2f(hz));
        float g2 = fmaf(gx, gx, fmaf(gy, gy, gz * gz));
        unsigned short sh = f2bf(g2), sl = f2bf(g2 - bf2f(sh));
        uint4 a0, a1, b0, b1;
        a0.x = pk(hx, hy); a0.y = pk(hz, lx); a0.z = pk(ly, lz); a0.w = pk(hx, hy);
        a1.x = pk(hz, sh); a1.y = pk(sl, ONE); a1.z = pk(ONE, lx); a1.w = pk(ly, lz);
        b0.x = pk(hx, hy); b0.y = pk(hz, hx); b0.z = pk(hy, hz); b0.w = pk(lx, ly);
        b1.x = pk(lz, ONE); b1.y = pk(ONE, sh); b1.z = pk(sl, lx); b1.w = pk(ly, lz);
        Ag[i] = a0; Ag[NPTS + i] = a1;
        Bf[i] = b0; Bf[NPTS + i] = b1;
    }
    minP[i] = 0x7F800000u;   // +inf
    minG[i] = 0x7F800000u;
}

// Min of 32 values (two accumulators), min3-shaped for v_min3 fusion.
__device__ inline float tree32(const f32x16 a, const f32x16 b) {
    float m0 = fminf(fminf(a[0],  a[1]),  a[2]);
    float m1 = fminf(fminf(a[3],  a[4]),  a[5]);
    float m2 = fminf(fminf(a[6],  a[7]),  a[8]);
    float m3 = fminf(fminf(a[9],  a[10]), a[11]);
    float m4 = fminf(fminf(a[12], a[13]), a[14]);
    float m5 = fminf(fminf(a[15], b[0]),  b[1]);
    float m6 = fminf(fminf(b[2],  b[3]),  b[4]);
    float m7 = fminf(fminf(b[5],  b[6]),  b[7]);
    float m8 = fminf(fminf(b[8],  b[9]),  b[10]);
    float m9 = fminf(fminf(b[11], b[12]), b[13]);
    float ma = fminf(b[14], b[15]);
    float n0 = fminf(fminf(m0, m1), m2);
    float n1 = fminf(fminf(m3, m4), m5);
    float n2 = fminf(fminf(m6, m7), m8);
    float n3 = fminf(fminf(m9, ma), n0);
    return fminf(fminf(n1, n2), n3);
}

// ---------------------------------------------------------------------------
// Main kernel: grid (32,16,2); block tile 512 A-rows x 1024 B-cols, 8 waves.
// z picks the pass (which cloud is on the lane axis). Wave w owns A-rows
// [w*64, w*64+64) as two 32-row fragments, hoisted out of the s-loop.
// C/D layout (HW-verified): col = lane&31, row = (reg&3)+8*(reg>>2)+4*(lane>>5)
// -> per-lane tree32 over both a-tiles = min over this wave's 64 A-rows for
// this lane's B-col; halves/waves merge in cminS via LDS atomicMin; blocks
// merge via global atomicMin and simply EXIT (no drain/ticket — visibility to
// the finalize dispatch is guaranteed by end-of-kernel release + stream order).
// ---------------------------------------------------------------------------
__global__ __launch_bounds__(BLOCK, 2) void chamfer_mfma_kernel(
    const uint4* __restrict__ Af, const uint4* __restrict__ Bf,
    const uint4* __restrict__ Ag, const uint4* __restrict__ Bp,
    unsigned int* __restrict__ minP, unsigned int* __restrict__ minG)
{
    const int tid  = threadIdx.x;
    const int lane = tid & 63;
    const int wv   = tid >> 6;
    const int half = lane >> 5;
    const int ln31 = lane & 31;

    const uint4* __restrict__ Aside;
    const uint4* __restrict__ Bside;
    unsigned int* __restrict__ outMin;
    if (blockIdx.z == 0) { Aside = Af; Bside = Bf; outMin = minG; }
    else                 { Aside = Ag; Bside = Bp; outMin = minP; }

    const int rowBase = blockIdx.x * ROWS_PER_BLOCK + wv * ROWS_PER_WAVE;
    const int colBase = blockIdx.y * COLS_PER_BLOCK;

    __shared__ uint4 sBf[2 * COLS_PER_BLOCK];      // 32 KB: [half][col]
    __shared__ unsigned int cminS[COLS_PER_BLOCK]; // 4 KB

    // Stage the block's B-side slice (both halves) + init col-min array.
    #pragma unroll
    for (int p = 0; p < (2 * COLS_PER_BLOCK) / BLOCK; ++p) {
        int idx = p * BLOCK + tid;
        int h = idx >> 10;          // /COLS_PER_BLOCK
        int c = idx & (COLS_PER_BLOCK - 1);
        sBf[idx] = Bside[h * NPTS + colBase + c];
    }
    for (int c = tid; c < COLS_PER_BLOCK; c += BLOCK)
        cminS[c] = 0x7F800000u;
    __syncthreads();

    const uint4* __restrict__ Ah = Aside + half * NPTS;
    const uint4* sB = sBf + half * COLS_PER_BLOCK;   // this lane's k-half

    // A fragments: both 32-row tiles, loaded once.
    bf16x8 af0 = __builtin_bit_cast(bf16x8, Ah[rowBase + ln31]);
    bf16x8 af1 = __builtin_bit_cast(bf16x8, Ah[rowBase + 32 + ln31]);

    const f32x16 zacc = {0.f,0.f,0.f,0.f, 0.f,0.f,0.f,0.f,
                         0.f,0.f,0.f,0.f, 0.f,0.f,0.f,0.f};

    #pragma unroll 2
    for (int s = 0; s < CSTEPS; ++s) {
        bf16x8 b0 = __builtin_bit_cast(bf16x8, sB[s * 64 + ln31]);
        bf16x8 b1 = __builtin_bit_cast(bf16x8, sB[s * 64 + 32 + ln31]);
        f32x16 p0 = __builtin_amdgcn_mfma_f32_32x32x16_bf16(af0, b0, zacc, 0, 0, 0);
        f32x16 q0 = __builtin_amdgcn_mfma_f32_32x32x16_bf16(af1, b0, zacc, 0, 0, 0);
        f32x16 p1 = __builtin_amdgcn_mfma_f32_32x32x16_bf16(af0, b1, zacc, 0, 0, 0);
        f32x16 q1 = __builtin_amdgcn_mfma_f32_32x32x16_bf16(af1, b1, zacc, 0, 0, 0);
        float c0 = fmaxf(tree32(p0, q0), 0.0f);
        float c1 = fmaxf(tree32(p1, q1), 0.0f);
        atomicMin(&cminS[s * 64 + ln31],      __float_as_uint(c0));
        atomicMin(&cminS[s * 64 + 32 + ln31], __float_as_uint(c1));
    }

    __syncthreads();
    #pragma unroll
    for (int p = 0; p < COLS_PER_BLOCK / BLOCK; ++p) {
        int c = p * BLOCK + tid;
        atomicMin(&outMin[colBase + c], cminS[c]);   // already clamped >= 0
    }
    // No drain, no ticket: end-of-dispatch release makes these visible to the
    // finalize kernel (stream-ordered).
}

// ---------------------------------------------------------------------------
// Finalize: one block, 1024 threads. Plain loads (prior dispatch's atomics
// are visible via stream order). Weighted sums + final scalar.
// ---------------------------------------------------------------------------
__global__ __launch_bounds__(1024) void finalize_kernel(
    const unsigned int* __restrict__ minP,
    const unsigned int* __restrict__ minG,
    const float* __restrict__ wpred, const float* __restrict__ wgt,
    float* __restrict__ out)
{
    const int tid  = threadIdx.x;
    const int lane = tid & 63;
    const int wv   = tid >> 6;

    float np = 0.f, dp = 0.f, ng = 0.f, dg = 0.f;
    #pragma unroll 4
    for (int i = tid; i < NPTS; i += 1024) {
        float v = __uint_as_float(minP[i]);
        float w = wpred[i];
        np = fmaf(w, v, np); dp += w;
        float u = __uint_as_float(minG[i]);
        float x = wgt[i];
        ng = fmaf(x, u, ng); dg += x;
    }
    #pragma unroll
    for (int off = 1; off < 64; off <<= 1) {
        np += __shfl_xor(np, off, 64);
        dp += __shfl_xor(dp, off, 64);
        ng += __shfl_xor(ng, off, 64);
        dg += __shfl_xor(dg, off, 64);
    }
    __shared__ float sred[4][16];
    if (lane == 0) { sred[0][wv] = np; sred[1][wv] = dp;
                     sred[2][wv] = ng; sred[3][wv] = dg; }
    __syncthreads();
    if (tid == 0) {
        float NP = 0.f, DP = 0.f, NG = 0.f, DG = 0.f;
        #pragma unroll
        for (int k = 0; k < 16; ++k) {
            NP += sred[0][k]; DP += sred[1][k];
            NG += sred[2][k]; DG += sred[3][k];
        }
        out[0] = NP / fmaxf(DP, 1e-9f) + NG / fmaxf(DG, 1e-9f);
    }
}

// ---------------------------------------------------------------------------
extern "C" void kernel_launch(void* const* d_in, const int* in_sizes, int n_in,
                              void* d_out, int out_size, void* d_ws, size_t ws_size,
                              hipStream_t stream)
{
    const float* pred  = (const float*)d_in[0];   // (P,3)
    const float* gt    = (const float*)d_in[1];   // (G,3)
    const float* wpred = (const float*)d_in[2];   // (P,)
    const float* wgt   = (const float*)d_in[3];   // (G,)
    float* out = (float*)d_out;

    // ws: Af|Bf|Ag|Bp (512K each) | minP(64K) | minG(64K)  (~2.13 MB)
    uint4* Af = (uint4*)d_ws;
    uint4* Bf = Af + 2 * NPTS;
    uint4* Ag = Bf + 2 * NPTS;
    uint4* Bp = Ag + 2 * NPTS;
    unsigned int* minP = (unsigned int*)(Bp + 2 * NPTS);
    unsigned int* minG = minP + NPTS;

    pack_init_kernel<<<NPTS / 256, 256, 0, stream>>>(
        pred, gt, Af, Bf, Ag, Bp, minP, minG);

    chamfer_mfma_kernel<<<dim3(NBX, NBY, 2), BLOCK, 0, stream>>>(
        Af, Bf, Ag, Bp, minP, minG);

    finalize_kernel<<<1, 1024, 0, stream>>>(minP, minG, wpred, wgt, out);
}